// Round 1
// baseline (960.310 us; speedup 1.0000x reference)
//
#include <hip/hip_runtime.h>
#include <hip/hip_bf16.h>
#include <math.h>

#define E_ 32
#define K_ 4
#define H_ 1024
#define I_ 1024
#define T_ 1024
#define TWO_I 2048
#define ALPHA_ 1.702f
#define BETA_ 1.0f

// ---------------- router: logits -> top4 -> softmax weights -> per-expert lists
__global__ void router_kernel(const float* __restrict__ hs,
                              const float* __restrict__ gw,
                              const float* __restrict__ gb,
                              int* __restrict__ counts,
                              int* __restrict__ token_list,
                              float* __restrict__ weight_list) {
    int t = blockIdx.x;
    int lane = threadIdx.x;
    __shared__ float logits[E_];
    if (lane < E_) {
        float acc = 0.f;
        const float* hrow = hs + (size_t)t * H_;
        for (int h = 0; h < H_; ++h)
            acc = fmaf(hrow[h], gw[h * E_ + lane], acc);
        logits[lane] = acc + gb[lane];
    }
    __syncthreads();
    if (lane == 0) {
        unsigned taken = 0u;
        int idx[K_]; float val[K_];
        for (int k = 0; k < K_; ++k) {
            float best = -INFINITY; int bi = 0;
            for (int e = 0; e < E_; ++e) {
                if (!((taken >> e) & 1u) && logits[e] > best) { best = logits[e]; bi = e; }
            }
            taken |= (1u << bi);
            idx[k] = bi; val[k] = best;
        }
        float m = val[0];           // first pick is the max
        float wv[K_]; float s = 0.f;
        for (int k = 0; k < K_; ++k) { wv[k] = expf(val[k] - m); s += wv[k]; }
        float inv = 1.f / s;
        for (int k = 0; k < K_; ++k) {
            int e = idx[k];
            int slot = atomicAdd(&counts[e], 1);
            token_list[e * T_ + slot] = t;
            weight_list[e * T_ + slot] = wv[k] * inv;
        }
    }
}

// ---------------- exclusive prefix sum over 32 counts
__global__ void scan_kernel(const int* __restrict__ counts, int* __restrict__ offsets) {
    if (threadIdx.x == 0) {
        int o = 0;
        for (int e = 0; e < E_; ++e) { offsets[e] = o; o += counts[e]; }
        offsets[E_] = o;
    }
}

// ---------------- compact per-expert lists into global-slot arrays
__global__ void compact_kernel(const int* __restrict__ counts,
                               const int* __restrict__ offsets,
                               const int* __restrict__ token_list,
                               const float* __restrict__ weight_list,
                               int* __restrict__ tok_of_slot,
                               float* __restrict__ w_of_slot) {
    int e = blockIdx.x;
    int cnt = counts[e];
    int off = offsets[e];
    for (int s = threadIdx.x; s < cnt; s += blockDim.x) {
        tok_of_slot[off + s] = token_list[e * T_ + s];
        w_of_slot[off + s]   = weight_list[e * T_ + s];
    }
}

// ---------------- GEMM1 + activation: act[g][i] = swiglu(hs[t]@w1[e] + b1[e])
// block: 256 thr; tile BM=64 rows x 32 act cols (=64 w1 cols); BK=32
__global__ __launch_bounds__(256) void gemm1_act_kernel(
    const float* __restrict__ hs, const float* __restrict__ w1,
    const float* __restrict__ b1, const int* __restrict__ counts,
    const int* __restrict__ offsets, const int* __restrict__ tok_of_slot,
    float* __restrict__ act) {
    int e = blockIdx.z;
    int cnt = counts[e];
    int m0 = blockIdx.y * 64;
    if (m0 >= cnt) return;
    int c0 = blockIdx.x * 32;               // act col base
    int off = offsets[e];
    const float* w1e = w1 + (size_t)e * H_ * TWO_I;

    __shared__ float As[64][33];
    __shared__ float Bs[32][64];

    int tid = threadIdx.x;
    int tx = tid & 31, ty = tid >> 5;

    float ga[8], ua[8];
#pragma unroll
    for (int r = 0; r < 8; ++r) { ga[r] = 0.f; ua[r] = 0.f; }

    for (int k0 = 0; k0 < H_; k0 += 32) {
#pragma unroll
        for (int i = 0; i < 8; ++i) {        // A: 64x32 gathered rows
            int l = tid + i * 256;
            int r = l >> 5, c = l & 31;
            int gr = m0 + r;
            float v = 0.f;
            if (gr < cnt) {
                int t = tok_of_slot[off + gr];
                v = hs[(size_t)t * H_ + k0 + c];
            }
            As[r][c] = v;
        }
#pragma unroll
        for (int i = 0; i < 8; ++i) {        // B: 32x64 w1 cols [2*c0, 2*c0+64)
            int l = tid + i * 256;
            int r = l >> 6, c = l & 63;
            Bs[r][c] = w1e[(size_t)(k0 + r) * TWO_I + c0 * 2 + c];
        }
        __syncthreads();
#pragma unroll
        for (int kk = 0; kk < 32; ++kk) {
            float bg = Bs[kk][2 * tx];
            float bu = Bs[kk][2 * tx + 1];
#pragma unroll
            for (int r = 0; r < 8; ++r) {
                float a = As[ty * 8 + r][kk];
                ga[r] = fmaf(a, bg, ga[r]);
                ua[r] = fmaf(a, bu, ua[r]);
            }
        }
        __syncthreads();
    }
    int col = c0 + tx;
    float bgate = b1[(size_t)e * TWO_I + 2 * col];
    float bup   = b1[(size_t)e * TWO_I + 2 * col + 1];
#pragma unroll
    for (int r = 0; r < 8; ++r) {
        int gr = m0 + ty * 8 + r;
        if (gr < cnt) {
            float gate = ga[r] + bgate;
            float up   = ua[r] + bup;
            float sig  = 1.f / (1.f + expf(-ALPHA_ * gate));
            act[(size_t)(off + gr) * I_ + col] = (up + BETA_) * gate * sig;
        }
    }
}

// ---------------- GEMM2 + weighted scatter: out[t] += w * (act[g]@w2[e] + b2[e])
// block: 256 thr; tile BM=64 x BN=64; BK=32; each thread 4x4
__global__ __launch_bounds__(256) void gemm2_scatter_kernel(
    const float* __restrict__ act, const float* __restrict__ w2,
    const float* __restrict__ b2, const int* __restrict__ counts,
    const int* __restrict__ offsets, const int* __restrict__ tok_of_slot,
    const float* __restrict__ w_of_slot, float* __restrict__ out) {
    int e = blockIdx.z;
    int cnt = counts[e];
    int m0 = blockIdx.y * 64;
    if (m0 >= cnt) return;
    int h0 = blockIdx.x * 64;
    int off = offsets[e];
    const float* w2e = w2 + (size_t)e * I_ * H_;

    __shared__ float As[64][33];
    __shared__ float Bs[32][64];

    int tid = threadIdx.x;
    int tcol = tid & 15, trow = tid >> 4;

    float acc[4][4];
#pragma unroll
    for (int i = 0; i < 4; ++i)
#pragma unroll
        for (int j = 0; j < 4; ++j) acc[i][j] = 0.f;

    for (int k0 = 0; k0 < I_; k0 += 32) {
#pragma unroll
        for (int i = 0; i < 8; ++i) {
            int l = tid + i * 256;
            int r = l >> 5, c = l & 31;
            int gr = m0 + r;
            As[r][c] = (gr < cnt) ? act[(size_t)(off + gr) * I_ + k0 + c] : 0.f;
        }
#pragma unroll
        for (int i = 0; i < 8; ++i) {
            int l = tid + i * 256;
            int r = l >> 6, c = l & 63;
            Bs[r][c] = w2e[(size_t)(k0 + r) * H_ + h0 + c];
        }
        __syncthreads();
#pragma unroll
        for (int kk = 0; kk < 32; ++kk) {
            float a[4], b[4];
#pragma unroll
            for (int i = 0; i < 4; ++i) a[i] = As[trow * 4 + i][kk];
#pragma unroll
            for (int j = 0; j < 4; ++j) b[j] = Bs[kk][tcol * 4 + j];
#pragma unroll
            for (int i = 0; i < 4; ++i)
#pragma unroll
                for (int j = 0; j < 4; ++j)
                    acc[i][j] = fmaf(a[i], b[j], acc[i][j]);
        }
        __syncthreads();
    }
#pragma unroll
    for (int i = 0; i < 4; ++i) {
        int gr = m0 + trow * 4 + i;
        if (gr >= cnt) continue;
        int g = off + gr;
        int t = tok_of_slot[g];
        float wgt = w_of_slot[g];
#pragma unroll
        for (int j = 0; j < 4; ++j) {
            int h = h0 + tcol * 4 + j;
            atomicAdd(&out[(size_t)t * H_ + h], wgt * (acc[i][j] + b2[(size_t)e * H_ + h]));
        }
    }
}

extern "C" void kernel_launch(void* const* d_in, const int* in_sizes, int n_in,
                              void* d_out, int out_size, void* d_ws, size_t ws_size,
                              hipStream_t stream) {
    const float* hs = (const float*)d_in[0];
    const float* gw = (const float*)d_in[1];
    const float* gb = (const float*)d_in[2];
    const float* w1 = (const float*)d_in[3];
    const float* b1 = (const float*)d_in[4];
    const float* w2 = (const float*)d_in[5];
    const float* b2 = (const float*)d_in[6];
    float* out = (float*)d_out;

    char* ws = (char*)d_ws;
    int*   counts      = (int*)ws;                          // 32 ints
    int*   offsets     = counts + 32;                       // 33 ints
    int*   tok_of_slot = (int*)(ws + 512);                  // 4096 ints
    float* w_of_slot   = (float*)(ws + 512 + 16384);        // 4096 f32
    int*   token_list  = (int*)(ws + 512 + 32768);          // 32*1024 ints
    float* weight_list = (float*)(ws + 512 + 32768 + 131072);// 32*1024 f32
    float* act         = (float*)(ws + (1 << 20));          // 4096*1024 f32 = 16MB

    hipMemsetAsync(counts, 0, 32 * sizeof(int), stream);
    hipMemsetAsync(d_out, 0, (size_t)out_size * sizeof(float), stream);

    router_kernel<<<T_, 64, 0, stream>>>(hs, gw, gb, counts, token_list, weight_list);
    scan_kernel<<<1, 64, 0, stream>>>(counts, offsets);
    compact_kernel<<<E_, 256, 0, stream>>>(counts, offsets, token_list, weight_list,
                                           tok_of_slot, w_of_slot);
    gemm1_act_kernel<<<dim3(I_ / 32, T_ / 64, E_), 256, 0, stream>>>(
        hs, w1, b1, counts, offsets, tok_of_slot, act);
    gemm2_scatter_kernel<<<dim3(H_ / 64, T_ / 64, E_), 256, 0, stream>>>(
        act, w2, b2, counts, offsets, tok_of_slot, w_of_slot, out);
}

// Round 2
// 534.922 us; speedup vs baseline: 1.7952x; 1.7952x over previous
//
#include <hip/hip_runtime.h>
#include <hip/hip_bf16.h>
#include <math.h>

#define E_ 32
#define K_ 4
#define H_ 1024
#define I_ 1024
#define T_ 1024
#define TWO_I 2048

typedef __attribute__((ext_vector_type(4))) float float4v;
typedef __attribute__((ext_vector_type(8))) short short8v;
typedef __attribute__((ext_vector_type(4))) short short4v;

__device__ __forceinline__ unsigned short f2bf(float f) {
    unsigned u = __float_as_uint(f);
    u = (u + 0x7FFFu + ((u >> 16) & 1u)) >> 16;   // RNE
    return (unsigned short)u;
}
__device__ __forceinline__ short4v cvt4(float4v v) {
    short4v r;
    r[0] = (short)f2bf(v[0]); r[1] = (short)f2bf(v[1]);
    r[2] = (short)f2bf(v[2]); r[3] = (short)f2bf(v[3]);
    return r;
}
// permuted position (in shorts) of a 4-aligned k-chunk within a 64-k row,
// matching the tr-read's k mapping: k = 32s + 16hi + 4g + j  ->  p = 32s + 8g + 4hi + j
__device__ __forceinline__ int permpos(int k4) {
    return ((k4 >> 5) << 5) + (((k4 >> 2) & 3) << 3) + (((k4 >> 4) & 1) << 2);
}

// ---------------- router: logits -> top4 -> softmax weights -> per-expert lists
__global__ void router_kernel(const float* __restrict__ hs,
                              const float* __restrict__ gw,
                              const float* __restrict__ gb,
                              int* __restrict__ counts,
                              int* __restrict__ token_list,
                              float* __restrict__ weight_list) {
    int t = blockIdx.x;
    int lane = threadIdx.x;
    __shared__ float logits[E_];
    if (lane < E_) {
        float acc = 0.f;
        const float* hrow = hs + (size_t)t * H_;
        for (int h = 0; h < H_; ++h)
            acc = fmaf(hrow[h], gw[h * E_ + lane], acc);
        logits[lane] = acc + gb[lane];
    }
    __syncthreads();
    if (lane == 0) {
        unsigned taken = 0u;
        int idx[K_]; float val[K_];
        for (int k = 0; k < K_; ++k) {
            float best = -INFINITY; int bi = 0;
            for (int e = 0; e < E_; ++e) {
                if (!((taken >> e) & 1u) && logits[e] > best) { best = logits[e]; bi = e; }
            }
            taken |= (1u << bi);
            idx[k] = bi; val[k] = best;
        }
        float m = val[0];
        float wv[K_]; float s = 0.f;
        for (int k = 0; k < K_; ++k) { wv[k] = expf(val[k] - m); s += wv[k]; }
        float inv = 1.f / s;
        for (int k = 0; k < K_; ++k) {
            int e = idx[k];
            int slot = atomicAdd(&counts[e], 1);
            token_list[e * T_ + slot] = t;
            weight_list[e * T_ + slot] = wv[k] * inv;
        }
    }
}

__global__ void scan_kernel(const int* __restrict__ counts, int* __restrict__ offsets) {
    if (threadIdx.x == 0) {
        int o = 0;
        for (int e = 0; e < E_; ++e) { offsets[e] = o; o += counts[e]; }
        offsets[E_] = o;
    }
}

__global__ void compact_kernel(const int* __restrict__ counts,
                               const int* __restrict__ offsets,
                               const int* __restrict__ token_list,
                               const float* __restrict__ weight_list,
                               int* __restrict__ tok_of_slot,
                               float* __restrict__ w_of_slot) {
    int e = blockIdx.x;
    int cnt = counts[e];
    int off = offsets[e];
    for (int s = threadIdx.x; s < cnt; s += blockDim.x) {
        tok_of_slot[off + s] = token_list[e * T_ + s];
        w_of_slot[off + s]   = weight_list[e * T_ + s];
    }
}

// ---------------- GEMM1 (bf16 MFMA) + swiglu: act[g][i] from hs@w1+b1
// block 256 (4 waves, 2m x 2n), tile BM=128 x BN=128 (w1 cols), BK=64
__global__ __launch_bounds__(256, 2) void gemm1_kernel(
    const float* __restrict__ hs, const float* __restrict__ w1,
    const float* __restrict__ b1, const int* __restrict__ counts,
    const int* __restrict__ offsets, const int* __restrict__ tok_of_slot,
    unsigned short* __restrict__ actb) {
    int e = blockIdx.z;
    int cnt = counts[e];
    int m0 = blockIdx.y * 128;
    if (m0 >= cnt) return;
    int cb = blockIdx.x * 128;            // w1 col base
    int off = offsets[e];
    const float* w1e = w1 + (size_t)e * H_ * TWO_I;

    __shared__ __align__(16) short As[128 * 64];   // [row][64] xor-swizzled, k-permuted
    __shared__ __align__(16) short Bs[8192];       // [nb(8)][kb(16)][4][16] subtiled

    int tid = threadIdx.x;
    int lane = tid & 63;
    int wid = tid >> 6;
    int wm = wid >> 1, wn = wid & 1;
    int g = lane >> 4;
    int l15 = lane & 15;

    unsigned b_base = (unsigned)(size_t)(&Bs[0]);
    unsigned baddr = b_base + (unsigned)(lane * 8) + (unsigned)(wn * 8192);

    float4v acc[4][4];
#pragma unroll
    for (int i = 0; i < 4; ++i)
#pragma unroll
        for (int j = 0; j < 4; ++j) acc[i][j] = (float4v){0.f, 0.f, 0.f, 0.f};

    for (int k0 = 0; k0 < H_; k0 += 64) {
        // stage A: 128 rows x 64 k (gathered token rows), fp32 -> bf16
#pragma unroll
        for (int i = 0; i < 8; ++i) {
            int c = i * 256 + tid;
            int row = c >> 4;
            int k4 = (c & 15) << 2;
            float4v v = {0.f, 0.f, 0.f, 0.f};
            int gr = m0 + row;
            if (gr < cnt) {
                int t = tok_of_slot[off + gr];
                v = *(const float4v*)(hs + (size_t)t * H_ + k0 + k4);
            }
            int sw = (row & 7) << 3;
            *(short4v*)&As[row * 64 + (permpos(k4) ^ sw)] = cvt4(v);
        }
        // stage B: 64 k-rows x 128 cols of w1, fp32 -> bf16, 4x16 subtiled
#pragma unroll
        for (int i = 0; i < 8; ++i) {
            int c = i * 256 + tid;
            int krow = c >> 5;
            int n4 = (c & 31) << 2;
            float4v v = *(const float4v*)(w1e + (size_t)(k0 + krow) * TWO_I + cb + n4);
            int st = (n4 >> 4) * 16 + (krow >> 2);
            *(short4v*)&Bs[st * 64 + (krow & 3) * 16 + (n4 & 15)] = cvt4(v);
        }
        __syncthreads();
#pragma unroll
        for (int s = 0; s < 2; ++s) {
            short8v a[4];
#pragma unroll
            for (int mi = 0; mi < 4; ++mi) {
                int row = wm * 64 + mi * 16 + l15;
                a[mi] = *(const short8v*)&As[row * 64 + ((s * 32 + g * 8) ^ ((row & 7) << 3))];
            }
            short4v bl[4], bh[4];
#pragma unroll
            for (int ni = 0; ni < 4; ++ni) {
                unsigned ad = baddr + (unsigned)(ni * 2048 + s * 1024);
                asm volatile("ds_read_b64_tr_b16 %0, %1" : "=v"(bl[ni]) : "v"(ad));
                asm volatile("ds_read_b64_tr_b16 %0, %1" : "=v"(bh[ni]) : "v"(ad + 512u));
            }
            asm volatile("s_waitcnt lgkmcnt(0)" ::: "memory");
            __builtin_amdgcn_sched_barrier(0);
#pragma unroll
            for (int ni = 0; ni < 4; ++ni) {
                short8v b;
                b[0] = bl[ni][0]; b[1] = bl[ni][1]; b[2] = bl[ni][2]; b[3] = bl[ni][3];
                b[4] = bh[ni][0]; b[5] = bh[ni][1]; b[6] = bh[ni][2]; b[7] = bh[ni][3];
#pragma unroll
                for (int mi = 0; mi < 4; ++mi)
                    acc[mi][ni] = __builtin_amdgcn_mfma_f32_16x16x32_bf16(a[mi], b, acc[mi][ni], 0, 0, 0);
            }
        }
        __syncthreads();
    }
    // epilogue: deinterleave gate/up (adjacent lanes), swiglu, store bf16 act
    const float* b1e = b1 + (size_t)e * TWO_I;
#pragma unroll
    for (int mi = 0; mi < 4; ++mi) {
#pragma unroll
        for (int r = 0; r < 4; ++r) {
            int gm = m0 + wm * 64 + mi * 16 + g * 4 + r;
#pragma unroll
            for (int ni = 0; ni < 4; ++ni) {
                float v = acc[mi][ni][r];
                float o = __shfl_xor(v, 1);
                if (!(lane & 1) && gm < cnt) {
                    int wc = cb + wn * 64 + ni * 16 + l15;   // even w1 col (gate)
                    float gate = v + b1e[wc];
                    float up   = o + b1e[wc + 1];
                    float sg = 1.f / (1.f + __expf(-1.702f * gate));
                    float av = (up + 1.f) * gate * sg;
                    actb[(size_t)(off + gm) * I_ + (wc >> 1)] = f2bf(av);
                }
            }
        }
    }
}

// ---------------- GEMM2 (bf16 MFMA) + weighted scatter
__global__ __launch_bounds__(256, 2) void gemm2_kernel(
    const unsigned short* __restrict__ actb, const float* __restrict__ w2,
    const float* __restrict__ b2, const int* __restrict__ counts,
    const int* __restrict__ offsets, const int* __restrict__ tok_of_slot,
    const float* __restrict__ w_of_slot, float* __restrict__ out) {
    int e = blockIdx.z;
    int cnt = counts[e];
    int m0 = blockIdx.y * 128;
    if (m0 >= cnt) return;
    int h0 = blockIdx.x * 128;
    int off = offsets[e];
    const float* w2e = w2 + (size_t)e * I_ * H_;

    __shared__ __align__(16) short As[128 * 64];
    __shared__ __align__(16) short Bs[8192];

    int tid = threadIdx.x;
    int lane = tid & 63;
    int wid = tid >> 6;
    int wm = wid >> 1, wn = wid & 1;
    int g = lane >> 4;
    int l15 = lane & 15;

    unsigned b_base = (unsigned)(size_t)(&Bs[0]);
    unsigned baddr = b_base + (unsigned)(lane * 8) + (unsigned)(wn * 8192);

    float4v acc[4][4];
#pragma unroll
    for (int i = 0; i < 4; ++i)
#pragma unroll
        for (int j = 0; j < 4; ++j) acc[i][j] = (float4v){0.f, 0.f, 0.f, 0.f};

    for (int k0 = 0; k0 < I_; k0 += 64) {
        // stage A: act bf16, permuted
#pragma unroll
        for (int i = 0; i < 4; ++i) {
            int c = i * 256 + tid;
            int row = c >> 3;
            int q = c & 7;
            short8v v = {0, 0, 0, 0, 0, 0, 0, 0};
            int gr = m0 + row;
            if (gr < cnt)
                v = *(const short8v*)(actb + (size_t)(off + gr) * I_ + k0 + q * 8);
            int sw = (row & 7) << 3;
            short4v lo, hi;
            lo[0] = v[0]; lo[1] = v[1]; lo[2] = v[2]; lo[3] = v[3];
            hi[0] = v[4]; hi[1] = v[5]; hi[2] = v[6]; hi[3] = v[7];
            *(short4v*)&As[row * 64 + (permpos(q * 8) ^ sw)] = lo;
            *(short4v*)&As[row * 64 + (permpos(q * 8 + 4) ^ sw)] = hi;
        }
        // stage B: w2 fp32 -> bf16 subtiled
#pragma unroll
        for (int i = 0; i < 8; ++i) {
            int c = i * 256 + tid;
            int krow = c >> 5;
            int n4 = (c & 31) << 2;
            float4v v = *(const float4v*)(w2e + (size_t)(k0 + krow) * H_ + h0 + n4);
            int st = (n4 >> 4) * 16 + (krow >> 2);
            *(short4v*)&Bs[st * 64 + (krow & 3) * 16 + (n4 & 15)] = cvt4(v);
        }
        __syncthreads();
#pragma unroll
        for (int s = 0; s < 2; ++s) {
            short8v a[4];
#pragma unroll
            for (int mi = 0; mi < 4; ++mi) {
                int row = wm * 64 + mi * 16 + l15;
                a[mi] = *(const short8v*)&As[row * 64 + ((s * 32 + g * 8) ^ ((row & 7) << 3))];
            }
            short4v bl[4], bh[4];
#pragma unroll
            for (int ni = 0; ni < 4; ++ni) {
                unsigned ad = baddr + (unsigned)(ni * 2048 + s * 1024);
                asm volatile("ds_read_b64_tr_b16 %0, %1" : "=v"(bl[ni]) : "v"(ad));
                asm volatile("ds_read_b64_tr_b16 %0, %1" : "=v"(bh[ni]) : "v"(ad + 512u));
            }
            asm volatile("s_waitcnt lgkmcnt(0)" ::: "memory");
            __builtin_amdgcn_sched_barrier(0);
#pragma unroll
            for (int ni = 0; ni < 4; ++ni) {
                short8v b;
                b[0] = bl[ni][0]; b[1] = bl[ni][1]; b[2] = bl[ni][2]; b[3] = bl[ni][3];
                b[4] = bh[ni][0]; b[5] = bh[ni][1]; b[6] = bh[ni][2]; b[7] = bh[ni][3];
#pragma unroll
                for (int mi = 0; mi < 4; ++mi)
                    acc[mi][ni] = __builtin_amdgcn_mfma_f32_16x16x32_bf16(a[mi], b, acc[mi][ni], 0, 0, 0);
            }
        }
        __syncthreads();
    }
    const float* b2e = b2 + (size_t)e * H_;
#pragma unroll
    for (int mi = 0; mi < 4; ++mi) {
#pragma unroll
        for (int r = 0; r < 4; ++r) {
            int gm = m0 + wm * 64 + mi * 16 + g * 4 + r;
            if (gm < cnt) {
                int gl = off + gm;
                int t = tok_of_slot[gl];
                float wgt = w_of_slot[gl];
#pragma unroll
                for (int ni = 0; ni < 4; ++ni) {
                    int h = h0 + wn * 64 + ni * 16 + l15;
                    atomicAdd(&out[(size_t)t * H_ + h], (acc[mi][ni][r] + b2e[h]) * wgt);
                }
            }
        }
    }
}

extern "C" void kernel_launch(void* const* d_in, const int* in_sizes, int n_in,
                              void* d_out, int out_size, void* d_ws, size_t ws_size,
                              hipStream_t stream) {
    const float* hs = (const float*)d_in[0];
    const float* gw = (const float*)d_in[1];
    const float* gb = (const float*)d_in[2];
    const float* w1 = (const float*)d_in[3];
    const float* b1 = (const float*)d_in[4];
    const float* w2 = (const float*)d_in[5];
    const float* b2 = (const float*)d_in[6];
    float* out = (float*)d_out;

    char* ws = (char*)d_ws;
    int*   counts      = (int*)ws;                            // 32 ints
    int*   offsets     = (int*)(ws + 128);                    // 33 ints
    int*   tok_of_slot = (int*)(ws + 512);                    // 4096 ints
    float* w_of_slot   = (float*)(ws + 512 + 16384);          // 4096 f32
    int*   token_list  = (int*)(ws + 512 + 32768);            // 32*1024 ints
    float* weight_list = (float*)(ws + 512 + 32768 + 131072); // 32*1024 f32
    unsigned short* actb = (unsigned short*)(ws + (1 << 20)); // 4096*1024 bf16 = 8MB

    hipMemsetAsync(counts, 0, 32 * sizeof(int), stream);
    hipMemsetAsync(d_out, 0, (size_t)out_size * sizeof(float), stream);

    router_kernel<<<T_, 64, 0, stream>>>(hs, gw, gb, counts, token_list, weight_list);
    scan_kernel<<<1, 64, 0, stream>>>(counts, offsets);
    compact_kernel<<<E_, 256, 0, stream>>>(counts, offsets, token_list, weight_list,
                                           tok_of_slot, w_of_slot);
    gemm1_kernel<<<dim3(TWO_I / 128, T_ / 128, E_), 256, 0, stream>>>(
        hs, w1, b1, counts, offsets, tok_of_slot, actb);
    gemm2_kernel<<<dim3(H_ / 128, T_ / 128, E_), 256, 0, stream>>>(
        actb, w2, b2, counts, offsets, tok_of_slot, w_of_slot, out);
}

// Round 3
// 250.869 us; speedup vs baseline: 3.8279x; 2.1323x over previous
//
#include <hip/hip_runtime.h>
#include <hip/hip_bf16.h>
#include <math.h>

#define E_ 32
#define K_ 4
#define H_ 1024
#define I_ 1024
#define T_ 1024
#define TWO_I 2048

typedef __attribute__((ext_vector_type(4))) float float4v;
typedef __attribute__((ext_vector_type(8))) short short8v;
typedef __attribute__((ext_vector_type(4))) short short4v;

__device__ __forceinline__ unsigned short f2bf(float f) {
    unsigned u = __float_as_uint(f);
    u = (u + 0x7FFFu + ((u >> 16) & 1u)) >> 16;   // RNE
    return (unsigned short)u;
}
__device__ __forceinline__ short4v cvt4(float4v v) {
    short4v r;
    r[0] = (short)f2bf(v[0]); r[1] = (short)f2bf(v[1]);
    r[2] = (short)f2bf(v[2]); r[3] = (short)f2bf(v[3]);
    return r;
}
// permuted position (in shorts) of a 4-aligned k-chunk within a 64-k row,
// matching tr-read's k mapping: k = 32s + 16hi + 4g + j -> p = 32s + 8g + 4hi + j
__device__ __forceinline__ int permpos(int k4) {
    return ((k4 >> 5) << 5) + (((k4 >> 2) & 3) << 3) + (((k4 >> 4) & 1) << 2);
}

// ---------------- router: 4 tokens/block, one wave per token, wave-parallel top-4
__global__ __launch_bounds__(256) void router_kernel(
    const float* __restrict__ hs, const float* __restrict__ gw,
    const float* __restrict__ gb, int* __restrict__ counts,
    int* __restrict__ token_list, float* __restrict__ weight_list) {
    int wv = threadIdx.x >> 6, lane = threadIdx.x & 63;
    int t = blockIdx.x * 4 + wv;
    int e = lane & 31;
    int half = lane >> 5;
    const float* hrow = hs + (size_t)t * H_;
    const float* gcol = gw + e;
    float a0 = 0.f, a1 = 0.f;
    int hb = half * 512;
#pragma unroll 4
    for (int h = 0; h < 512; h += 2) {
        a0 = fmaf(hrow[hb + h],     gcol[(size_t)(hb + h) * E_], a0);
        a1 = fmaf(hrow[hb + h + 1], gcol[(size_t)(hb + h + 1) * E_], a1);
    }
    float part = a0 + a1;
    part += __shfl_xor(part, 32);
    float cur = part + gb[e];

    int idx4[K_]; float val4[K_];
#pragma unroll
    for (int k = 0; k < K_; ++k) {
        float m = cur;
#pragma unroll
        for (int d = 1; d < 64; d <<= 1) m = fmaxf(m, __shfl_xor(m, d));
        unsigned long long b = __ballot(cur == m);
        int l = __ffsll(b) - 1;          // lowest lane with max -> lowest expert idx
        idx4[k] = l & 31; val4[k] = m;
        if (e == (l & 31)) cur = -INFINITY;
    }
    float mx = val4[0], s = 0.f, wv4[K_];
#pragma unroll
    for (int k = 0; k < K_; ++k) { wv4[k] = expf(val4[k] - mx); s += wv4[k]; }
    float inv = 1.f / s;
    if (lane < K_) {
        int ex = idx4[lane];
        int slot = atomicAdd(&counts[ex], 1);
        token_list[ex * T_ + slot] = t;
        weight_list[ex * T_ + slot] = wv4[lane] * inv;
    }
}

__global__ void scan_kernel(const int* __restrict__ counts, int* __restrict__ offsets) {
    if (threadIdx.x == 0) {
        int o = 0;
        for (int e = 0; e < E_; ++e) { offsets[e] = o; o += counts[e]; }
        offsets[E_] = o;
    }
}

__global__ void compact_kernel(const int* __restrict__ counts,
                               const int* __restrict__ offsets,
                               const int* __restrict__ token_list,
                               const float* __restrict__ weight_list,
                               int* __restrict__ tok_of_slot,
                               float* __restrict__ w_of_slot) {
    int e = blockIdx.x;
    int cnt = counts[e];
    int off = offsets[e];
    for (int s = threadIdx.x; s < cnt; s += blockDim.x) {
        tok_of_slot[off + s] = token_list[e * T_ + s];
        w_of_slot[off + s]   = weight_list[e * T_ + s];
    }
}

// ---------------- GEMM1 (bf16 MFMA, pipelined) + swiglu
// BM=128 x BN=128 (w1 cols), BK=64; 4 waves (2m x 2n)
__global__ __launch_bounds__(256, 2) void gemm1_kernel(
    const float* __restrict__ hs, const float* __restrict__ w1,
    const float* __restrict__ b1, const int* __restrict__ counts,
    const int* __restrict__ offsets, const int* __restrict__ tok_of_slot,
    unsigned short* __restrict__ actb) {
    int e = blockIdx.z;
    int cnt = counts[e];
    int m0 = blockIdx.y * 128;
    if (m0 >= cnt) return;
    int cb = blockIdx.x * 128;
    int off = offsets[e];
    const float* w1e = w1 + (size_t)e * H_ * TWO_I;

    __shared__ __align__(16) short As[128 * 64];
    __shared__ __align__(16) short Bs[8192];

    int tid = threadIdx.x;
    int lane = tid & 63;
    int wid = tid >> 6;
    int wm = wid >> 1, wn = wid & 1;
    int g = lane >> 4;
    int l15 = lane & 15;
    unsigned baddr = (unsigned)(size_t)(&Bs[0]) + (unsigned)(lane * 8) + (unsigned)(wn * 8192);

    // A: 8 float4/thread, static row/addr precompute
    int k4 = (tid & 15) << 2;
    const float* aptr[8]; int awidx[8];
#pragma unroll
    for (int i = 0; i < 8; ++i) {
        int row = i * 16 + (tid >> 4);
        int gr = m0 + row;
        aptr[i] = (gr < cnt) ? hs + (size_t)tok_of_slot[off + gr] * H_ + k4 : nullptr;
        awidx[i] = row * 64 + (permpos(k4) ^ ((row & 7) << 3));
    }
    // B: 8 float4/thread
    int n4 = (tid & 31) << 2;
    const float* bptr[8]; int bwidx[8];
#pragma unroll
    for (int i = 0; i < 8; ++i) {
        int krow = i * 8 + (tid >> 5);
        bptr[i] = w1e + (size_t)krow * TWO_I + cb + n4;
        bwidx[i] = ((n4 >> 4) * 16 + (krow >> 2)) * 64 + (krow & 3) * 16 + (n4 & 15);
    }

    float4v acc[4][4];
#pragma unroll
    for (int i = 0; i < 4; ++i)
#pragma unroll
        for (int j = 0; j < 4; ++j) acc[i][j] = (float4v){0.f, 0.f, 0.f, 0.f};

    float4v ra[8], rb[8];
    const float4v z4 = {0.f, 0.f, 0.f, 0.f};
#pragma unroll
    for (int i = 0; i < 8; ++i) ra[i] = aptr[i] ? *(const float4v*)(aptr[i]) : z4;
#pragma unroll
    for (int i = 0; i < 8; ++i) rb[i] = *(const float4v*)(bptr[i]);

#pragma unroll 1
    for (int k0 = 0; k0 < H_; k0 += 64) {
        // convert + LDS write (compiler inserts vmcnt waits)
#pragma unroll
        for (int i = 0; i < 8; ++i) *(short4v*)&As[awidx[i]] = cvt4(ra[i]);
#pragma unroll
        for (int i = 0; i < 8; ++i) *(short4v*)&Bs[bwidx[i]] = cvt4(rb[i]);
        __syncthreads();
        // issue next tile's loads (in flight during compute)
        if (k0 + 64 < H_) {
            int kn = k0 + 64;
#pragma unroll
            for (int i = 0; i < 8; ++i) ra[i] = aptr[i] ? *(const float4v*)(aptr[i] + kn) : z4;
#pragma unroll
            for (int i = 0; i < 8; ++i) rb[i] = *(const float4v*)(bptr[i] + (size_t)kn * TWO_I);
        }
        __builtin_amdgcn_sched_barrier(0);   // keep loads issued before compute
#pragma unroll
        for (int s = 0; s < 2; ++s) {
            short8v a[4];
#pragma unroll
            for (int mi = 0; mi < 4; ++mi) {
                int row = wm * 64 + mi * 16 + l15;
                a[mi] = *(const short8v*)&As[row * 64 + ((s * 32 + g * 8) ^ ((row & 7) << 3))];
            }
            short4v bl[4], bh[4];
#pragma unroll
            for (int ni = 0; ni < 4; ++ni) {
                unsigned ad = baddr + (unsigned)(ni * 2048 + s * 1024);
                asm volatile("ds_read_b64_tr_b16 %0, %1" : "=v"(bl[ni]) : "v"(ad));
                asm volatile("ds_read_b64_tr_b16 %0, %1" : "=v"(bh[ni]) : "v"(ad + 512u));
            }
            asm volatile("s_waitcnt lgkmcnt(0)" ::: "memory");
            __builtin_amdgcn_sched_barrier(0);
#pragma unroll
            for (int ni = 0; ni < 4; ++ni) {
                short8v b;
                b[0] = bl[ni][0]; b[1] = bl[ni][1]; b[2] = bl[ni][2]; b[3] = bl[ni][3];
                b[4] = bh[ni][0]; b[5] = bh[ni][1]; b[6] = bh[ni][2]; b[7] = bh[ni][3];
#pragma unroll
                for (int mi = 0; mi < 4; ++mi)
                    acc[mi][ni] = __builtin_amdgcn_mfma_f32_16x16x32_bf16(a[mi], b, acc[mi][ni], 0, 0, 0);
            }
        }
        __syncthreads();
    }
    // epilogue: deinterleave gate/up, swiglu, store bf16 act
    const float* b1e = b1 + (size_t)e * TWO_I;
#pragma unroll
    for (int mi = 0; mi < 4; ++mi) {
#pragma unroll
        for (int r = 0; r < 4; ++r) {
            int gm = m0 + wm * 64 + mi * 16 + g * 4 + r;
#pragma unroll
            for (int ni = 0; ni < 4; ++ni) {
                float v = acc[mi][ni][r];
                float o = __shfl_xor(v, 1);
                if (!(lane & 1) && gm < cnt) {
                    int wc = cb + wn * 64 + ni * 16 + l15;   // even w1 col (gate)
                    float gate = v + b1e[wc];
                    float up   = o + b1e[wc + 1];
                    float sg = 1.f / (1.f + __expf(-1.702f * gate));
                    float av = (up + 1.f) * gate * sg;
                    actb[(size_t)(off + gm) * I_ + (wc >> 1)] = f2bf(av);
                }
            }
        }
    }
}

// ---------------- GEMM2 (bf16 MFMA, pipelined, K-split x2) + weighted scatter
// BM=128 x BN=128 (h cols), BK=64; grid.x = 8 n-tiles * 2 k-splits
__global__ __launch_bounds__(256, 2) void gemm2_kernel(
    const unsigned short* __restrict__ actb, const float* __restrict__ w2,
    const float* __restrict__ b2, const int* __restrict__ counts,
    const int* __restrict__ offsets, const int* __restrict__ tok_of_slot,
    const float* __restrict__ w_of_slot, float* __restrict__ out) {
    int e = blockIdx.z;
    int cnt = counts[e];
    int m0 = blockIdx.y * 128;
    if (m0 >= cnt) return;
    int h0 = (blockIdx.x >> 1) * 128;
    int kbase = (blockIdx.x & 1) * 512;
    int off = offsets[e];
    const float* w2e = w2 + (size_t)e * I_ * H_;

    __shared__ __align__(16) short As[128 * 64];
    __shared__ __align__(16) short Bs[8192];

    int tid = threadIdx.x;
    int lane = tid & 63;
    int wid = tid >> 6;
    int wm = wid >> 1, wn = wid & 1;
    int g = lane >> 4;
    int l15 = lane & 15;
    unsigned baddr = (unsigned)(size_t)(&Bs[0]) + (unsigned)(lane * 8) + (unsigned)(wn * 8192);

    // A: 4 short8/thread from actb
    int q = tid & 7;
    const unsigned short* aptr[4]; int aw0[4], aw1[4];
#pragma unroll
    for (int i = 0; i < 4; ++i) {
        int row = i * 32 + (tid >> 3);
        int gr = m0 + row;
        aptr[i] = (gr < cnt) ? actb + (size_t)(off + gr) * I_ + kbase + q * 8 : nullptr;
        int sw = (row & 7) << 3;
        aw0[i] = row * 64 + (permpos(q * 8) ^ sw);
        aw1[i] = row * 64 + (permpos(q * 8 + 4) ^ sw);
    }
    // B: 8 float4/thread from w2
    int n4 = (tid & 31) << 2;
    const float* bptr[8]; int bwidx[8];
#pragma unroll
    for (int i = 0; i < 8; ++i) {
        int krow = i * 8 + (tid >> 5);
        bptr[i] = w2e + (size_t)(kbase + krow) * H_ + h0 + n4;
        bwidx[i] = ((n4 >> 4) * 16 + (krow >> 2)) * 64 + (krow & 3) * 16 + (n4 & 15);
    }

    float4v acc[4][4];
#pragma unroll
    for (int i = 0; i < 4; ++i)
#pragma unroll
        for (int j = 0; j < 4; ++j) acc[i][j] = (float4v){0.f, 0.f, 0.f, 0.f};

    short8v ra[4]; float4v rb[8];
    const short8v z8 = {0, 0, 0, 0, 0, 0, 0, 0};
#pragma unroll
    for (int i = 0; i < 4; ++i) ra[i] = aptr[i] ? *(const short8v*)(aptr[i]) : z8;
#pragma unroll
    for (int i = 0; i < 8; ++i) rb[i] = *(const float4v*)(bptr[i]);

#pragma unroll 1
    for (int k0 = 0; k0 < 512; k0 += 64) {
#pragma unroll
        for (int i = 0; i < 4; ++i) {
            short8v v = ra[i];
            short4v lo, hi;
            lo[0] = v[0]; lo[1] = v[1]; lo[2] = v[2]; lo[3] = v[3];
            hi[0] = v[4]; hi[1] = v[5]; hi[2] = v[6]; hi[3] = v[7];
            *(short4v*)&As[aw0[i]] = lo;
            *(short4v*)&As[aw1[i]] = hi;
        }
#pragma unroll
        for (int i = 0; i < 8; ++i) *(short4v*)&Bs[bwidx[i]] = cvt4(rb[i]);
        __syncthreads();
        if (k0 + 64 < 512) {
            int kn = k0 + 64;
#pragma unroll
            for (int i = 0; i < 4; ++i) ra[i] = aptr[i] ? *(const short8v*)(aptr[i] + kn) : z8;
#pragma unroll
            for (int i = 0; i < 8; ++i) rb[i] = *(const float4v*)(bptr[i] + (size_t)kn * H_);
        }
        __builtin_amdgcn_sched_barrier(0);
#pragma unroll
        for (int s = 0; s < 2; ++s) {
            short8v a[4];
#pragma unroll
            for (int mi = 0; mi < 4; ++mi) {
                int row = wm * 64 + mi * 16 + l15;
                a[mi] = *(const short8v*)&As[row * 64 + ((s * 32 + g * 8) ^ ((row & 7) << 3))];
            }
            short4v bl[4], bh[4];
#pragma unroll
            for (int ni = 0; ni < 4; ++ni) {
                unsigned ad = baddr + (unsigned)(ni * 2048 + s * 1024);
                asm volatile("ds_read_b64_tr_b16 %0, %1" : "=v"(bl[ni]) : "v"(ad));
                asm volatile("ds_read_b64_tr_b16 %0, %1" : "=v"(bh[ni]) : "v"(ad + 512u));
            }
            asm volatile("s_waitcnt lgkmcnt(0)" ::: "memory");
            __builtin_amdgcn_sched_barrier(0);
#pragma unroll
            for (int ni = 0; ni < 4; ++ni) {
                short8v b;
                b[0] = bl[ni][0]; b[1] = bl[ni][1]; b[2] = bl[ni][2]; b[3] = bl[ni][3];
                b[4] = bh[ni][0]; b[5] = bh[ni][1]; b[6] = bh[ni][2]; b[7] = bh[ni][3];
#pragma unroll
                for (int mi = 0; mi < 4; ++mi)
                    acc[mi][ni] = __builtin_amdgcn_mfma_f32_16x16x32_bf16(a[mi], b, acc[mi][ni], 0, 0, 0);
            }
        }
        __syncthreads();
    }
    const float* b2e = b2 + (size_t)e * H_;
    bool addbias = (kbase == 0);
#pragma unroll
    for (int mi = 0; mi < 4; ++mi) {
#pragma unroll
        for (int r = 0; r < 4; ++r) {
            int gm = m0 + wm * 64 + mi * 16 + g * 4 + r;
            if (gm < cnt) {
                int gl = off + gm;
                int t = tok_of_slot[gl];
                float wgt = w_of_slot[gl];
#pragma unroll
                for (int ni = 0; ni < 4; ++ni) {
                    int h = h0 + wn * 64 + ni * 16 + l15;
                    float v = acc[mi][ni][r];
                    if (addbias) v += b2e[h];
                    atomicAdd(&out[(size_t)t * H_ + h], v * wgt);
                }
            }
        }
    }
}

extern "C" void kernel_launch(void* const* d_in, const int* in_sizes, int n_in,
                              void* d_out, int out_size, void* d_ws, size_t ws_size,
                              hipStream_t stream) {
    const float* hs = (const float*)d_in[0];
    const float* gw = (const float*)d_in[1];
    const float* gb = (const float*)d_in[2];
    const float* w1 = (const float*)d_in[3];
    const float* b1 = (const float*)d_in[4];
    const float* w2 = (const float*)d_in[5];
    const float* b2 = (const float*)d_in[6];
    float* out = (float*)d_out;

    char* ws = (char*)d_ws;
    int*   counts      = (int*)ws;                            // 32 ints
    int*   offsets     = (int*)(ws + 128);                    // 33 ints
    int*   tok_of_slot = (int*)(ws + 512);                    // 4096 ints
    float* w_of_slot   = (float*)(ws + 512 + 16384);          // 4096 f32
    int*   token_list  = (int*)(ws + 512 + 32768);            // 32*1024 ints
    float* weight_list = (float*)(ws + 512 + 32768 + 131072); // 32*1024 f32
    unsigned short* actb = (unsigned short*)(ws + (1 << 20)); // 4096*1024 bf16 = 8MB

    hipMemsetAsync(counts, 0, 32 * sizeof(int), stream);
    hipMemsetAsync(d_out, 0, (size_t)out_size * sizeof(float), stream);

    router_kernel<<<T_ / 4, 256, 0, stream>>>(hs, gw, gb, counts, token_list, weight_list);
    scan_kernel<<<1, 64, 0, stream>>>(counts, offsets);
    compact_kernel<<<E_, 256, 0, stream>>>(counts, offsets, token_list, weight_list,
                                           tok_of_slot, w_of_slot);
    gemm1_kernel<<<dim3(TWO_I / 128, T_ / 128, E_), 256, 0, stream>>>(
        hs, w1, b1, counts, offsets, tok_of_slot, actb);
    gemm2_kernel<<<dim3((H_ / 128) * 2, T_ / 128, E_), 256, 0, stream>>>(
        actb, w2, b2, counts, offsets, tok_of_slot, w_of_slot, out);
}

// Round 4
// 214.807 us; speedup vs baseline: 4.4706x; 1.1679x over previous
//
#include <hip/hip_runtime.h>
#include <hip/hip_bf16.h>
#include <math.h>

#define E_ 32
#define K_ 4
#define H_ 1024
#define I_ 1024
#define T_ 1024
#define TWO_I 2048

typedef __attribute__((ext_vector_type(4))) float float4v;
typedef __attribute__((ext_vector_type(8))) short short8v;
typedef __attribute__((ext_vector_type(4))) short short4v;

__device__ __forceinline__ unsigned short f2bf(float f) {
    unsigned u = __float_as_uint(f);
    u = (u + 0x7FFFu + ((u >> 16) & 1u)) >> 16;   // RNE
    return (unsigned short)u;
}
__device__ __forceinline__ short4v cvt4(float4v v) {
    short4v r;
    r[0] = (short)f2bf(v[0]); r[1] = (short)f2bf(v[1]);
    r[2] = (short)f2bf(v[2]); r[3] = (short)f2bf(v[3]);
    return r;
}
// permuted position (shorts) of a 4-aligned k-chunk in a 64-k row, matching
// tr-read k map: k = 32s + 16hi + 4g + j -> p = 32s + 8g + 4hi + j
__device__ __forceinline__ int permpos(int k4) {
    return ((k4 >> 5) << 5) + (((k4 >> 2) & 3) << 3) + (((k4 >> 4) & 1) << 2);
}

// ---------------- router: 4 tokens/block, one wave/token, wave-parallel top-4
__global__ __launch_bounds__(256) void router_kernel(
    const float* __restrict__ hs, const float* __restrict__ gw,
    const float* __restrict__ gb, int* __restrict__ counts,
    int* __restrict__ token_list, float* __restrict__ weight_list) {
    int wv = threadIdx.x >> 6, lane = threadIdx.x & 63;
    int t = blockIdx.x * 4 + wv;
    int e = lane & 31;
    int half = lane >> 5;
    const float* hrow = hs + (size_t)t * H_;
    const float* gcol = gw + e;
    float a0 = 0.f, a1 = 0.f;
    int hb = half * 512;
#pragma unroll 4
    for (int h = 0; h < 512; h += 2) {
        a0 = fmaf(hrow[hb + h],     gcol[(size_t)(hb + h) * E_], a0);
        a1 = fmaf(hrow[hb + h + 1], gcol[(size_t)(hb + h + 1) * E_], a1);
    }
    float part = a0 + a1;
    part += __shfl_xor(part, 32);
    float cur = part + gb[e];

    int idx4[K_]; float val4[K_];
#pragma unroll
    for (int k = 0; k < K_; ++k) {
        float m = cur;
#pragma unroll
        for (int d = 1; d < 64; d <<= 1) m = fmaxf(m, __shfl_xor(m, d));
        unsigned long long b = __ballot(cur == m);
        int l = __ffsll(b) - 1;          // lowest lane -> lowest expert idx (tie-break)
        idx4[k] = l & 31; val4[k] = m;
        if (e == (l & 31)) cur = -INFINITY;
    }
    float mx = val4[0], s = 0.f, wv4[K_];
#pragma unroll
    for (int k = 0; k < K_; ++k) { wv4[k] = expf(val4[k] - mx); s += wv4[k]; }
    float inv = 1.f / s;
    if (lane < K_) {
        int ex = idx4[lane];
        int slot = atomicAdd(&counts[ex], 1);
        token_list[ex * T_ + slot] = t;
        weight_list[ex * T_ + slot] = wv4[lane] * inv;
    }
}

// ---------------- GEMM1 (bf16 MFMA, dbuf pipeline) + swiglu
// BM=128 x BN=64 (w1 cols), BK=64; 4 waves (2m x 2n); 1 barrier/K-step
#define G1_COMPUTE(BUF)                                                        \
    _Pragma("unroll")                                                          \
    for (int s = 0; s < 2; ++s) {                                              \
        short8v afr[4];                                                        \
        _Pragma("unroll")                                                      \
        for (int mi = 0; mi < 4; ++mi) {                                       \
            int row = wm * 64 + mi * 16 + l15;                                 \
            afr[mi] = *(const short8v*)&As[BUF][row * 64 + ((s * 32 + g * 8) ^ sw)]; \
        }                                                                      \
        short4v bl[2], bh[2];                                                  \
        _Pragma("unroll")                                                      \
        for (int ni = 0; ni < 2; ++ni) {                                       \
            unsigned ad = ((BUF) ? trb1 : trb0) + (unsigned)(ni * 2048 + s * 1024); \
            asm volatile("ds_read_b64_tr_b16 %0, %1" : "=v"(bl[ni]) : "v"(ad));     \
            asm volatile("ds_read_b64_tr_b16 %0, %1" : "=v"(bh[ni]) : "v"(ad + 512u)); \
        }                                                                      \
        asm volatile("s_waitcnt lgkmcnt(0)" ::: "memory");                     \
        __builtin_amdgcn_sched_barrier(0);                                     \
        _Pragma("unroll")                                                      \
        for (int ni = 0; ni < 2; ++ni) {                                       \
            short8v b;                                                         \
            b[0] = bl[ni][0]; b[1] = bl[ni][1]; b[2] = bl[ni][2]; b[3] = bl[ni][3]; \
            b[4] = bh[ni][0]; b[5] = bh[ni][1]; b[6] = bh[ni][2]; b[7] = bh[ni][3]; \
            _Pragma("unroll")                                                  \
            for (int mi = 0; mi < 4; ++mi)                                     \
                acc[mi][ni] = __builtin_amdgcn_mfma_f32_16x16x32_bf16(afr[mi], b, acc[mi][ni], 0, 0, 0); \
        }                                                                      \
    }

#define G1_STEP(BUF, KN, ISLAST)                                               \
    {                                                                          \
        __syncthreads();                                                       \
        if (!(ISLAST)) {                                                       \
            _Pragma("unroll")                                                  \
            for (int i = 0; i < 8; ++i)                                        \
                ra[i] = aptr[i] ? *(const float4v*)(aptr[i] + (KN)) : z4;      \
            _Pragma("unroll")                                                  \
            for (int i = 0; i < 4; ++i)                                        \
                rb[i] = *(const float4v*)(bptrB + (size_t)(KN)*TWO_I + (size_t)(i * 16) * TWO_I); \
        }                                                                      \
        __builtin_amdgcn_sched_barrier(0);                                     \
        G1_COMPUTE(BUF)                                                        \
        if (!(ISLAST)) {                                                       \
            _Pragma("unroll")                                                  \
            for (int i = 0; i < 8; ++i) *(short4v*)&As[(BUF) ^ 1][awidx[i]] = cvt4(ra[i]); \
            _Pragma("unroll")                                                  \
            for (int i = 0; i < 4; ++i) *(short4v*)&Bs[(BUF) ^ 1][bwidx[i]] = cvt4(rb[i]); \
        }                                                                      \
    }

__global__ __launch_bounds__(256, 3) void gemm1_kernel(
    const float* __restrict__ hs, const float* __restrict__ w1,
    const float* __restrict__ b1, const int* __restrict__ counts,
    const int* __restrict__ token_list, unsigned short* __restrict__ actb) {
    int e = blockIdx.z;
    int cnt = counts[e];
    int m0 = blockIdx.y * 128;
    if (m0 >= cnt) return;
    int cb = blockIdx.x * 64;              // w1 col base
    const float* w1e = w1 + (size_t)e * H_ * TWO_I;
    const int* tl = token_list + e * T_;

    __shared__ __align__(16) short As[2][128 * 64];  // 32 KB
    __shared__ __align__(16) short Bs[2][64 * 64];   // 16 KB

    int tid = threadIdx.x;
    int lane = tid & 63;
    int wid = tid >> 6;
    int wm = wid >> 1, wn = wid & 1;
    int g = lane >> 4;
    int l15 = lane & 15;
    int sw = (l15 & 7) << 3;
    unsigned trb0 = (unsigned)(size_t)(&Bs[0][0]) + (unsigned)(lane * 8) + (unsigned)(wn * 4096);
    unsigned trb1 = (unsigned)(size_t)(&Bs[1][0]) + (unsigned)(lane * 8) + (unsigned)(wn * 4096);

    // A: 8 float4/thread (gathered token rows)
    int k4 = (tid & 15) << 2;
    const float* aptr[8]; int awidx[8];
#pragma unroll
    for (int i = 0; i < 8; ++i) {
        int row = i * 16 + (tid >> 4);
        int gr = m0 + row;
        aptr[i] = (gr < cnt) ? hs + (size_t)tl[gr] * H_ + k4 : nullptr;
        awidx[i] = row * 64 + (permpos(k4) ^ ((row & 7) << 3));
    }
    // B: 4 float4/thread; rows (tid>>4) + 16i, cols (tid&15)*4
    const float* bptrB = w1e + (size_t)(tid >> 4) * TWO_I + cb + k4;
    int bwidx[4];
#pragma unroll
    for (int i = 0; i < 4; ++i) {
        int krow = i * 16 + (tid >> 4);
        bwidx[i] = ((k4 >> 4) * 16 + (krow >> 2)) * 64 + (krow & 3) * 16 + (k4 & 15);
    }

    float4v acc[4][2];
#pragma unroll
    for (int i = 0; i < 4; ++i)
#pragma unroll
        for (int j = 0; j < 2; ++j) acc[i][j] = (float4v){0.f, 0.f, 0.f, 0.f};

    float4v ra[8], rb[4];
    const float4v z4 = {0.f, 0.f, 0.f, 0.f};
    // prologue: tile 0 -> buf 0
#pragma unroll
    for (int i = 0; i < 8; ++i) ra[i] = aptr[i] ? *(const float4v*)(aptr[i]) : z4;
#pragma unroll
    for (int i = 0; i < 4; ++i) rb[i] = *(const float4v*)(bptrB + (size_t)(i * 16) * TWO_I);
#pragma unroll
    for (int i = 0; i < 8; ++i) *(short4v*)&As[0][awidx[i]] = cvt4(ra[i]);
#pragma unroll
    for (int i = 0; i < 4; ++i) *(short4v*)&Bs[0][bwidx[i]] = cvt4(rb[i]);

#pragma unroll 1
    for (int kk = 0; kk < H_; kk += 128) {
        G1_STEP(0, kk + 64, false)
        G1_STEP(1, kk + 128, (kk + 128) >= H_)
    }

    // epilogue: deinterleave gate/up (adjacent lanes), swiglu, store bf16 act
    const float* b1e = b1 + (size_t)e * TWO_I;
#pragma unroll
    for (int mi = 0; mi < 4; ++mi) {
#pragma unroll
        for (int r = 0; r < 4; ++r) {
            int gm = m0 + wm * 64 + mi * 16 + g * 4 + r;
#pragma unroll
            for (int ni = 0; ni < 2; ++ni) {
                float v = acc[mi][ni][r];
                float o = __shfl_xor(v, 1);
                if (!(lane & 1) && gm < cnt) {
                    int wc = cb + wn * 32 + ni * 16 + l15;   // even w1 col (gate)
                    float gate = v + b1e[wc];
                    float up   = o + b1e[wc + 1];
                    float sg = 1.f / (1.f + __expf(-1.702f * gate));
                    float av = (up + 1.f) * gate * sg;
                    actb[(size_t)(e * T_ + gm) * I_ + (wc >> 1)] = f2bf(av);
                }
            }
        }
    }
}

// ---------------- GEMM2 (bf16 MFMA, dbuf pipeline, K-split x2) + weighted scatter
#define G2_STEP(BUF, KN, ISLAST)                                               \
    {                                                                          \
        __syncthreads();                                                       \
        if (!(ISLAST)) {                                                       \
            _Pragma("unroll")                                                  \
            for (int i = 0; i < 4; ++i)                                        \
                ra2[i] = aptr[i] ? *(const short8v*)(aptr[i] + (KN)) : z8;     \
            _Pragma("unroll")                                                  \
            for (int i = 0; i < 4; ++i)                                        \
                rb[i] = *(const float4v*)(bptrB + (size_t)(KN)*H_ + (size_t)(i * 16) * H_); \
        }                                                                      \
        __builtin_amdgcn_sched_barrier(0);                                     \
        G1_COMPUTE(BUF)                                                        \
        if (!(ISLAST)) {                                                       \
            _Pragma("unroll")                                                  \
            for (int i = 0; i < 4; ++i) {                                      \
                short8v v = ra2[i];                                            \
                short4v lo, hi;                                                \
                lo[0] = v[0]; lo[1] = v[1]; lo[2] = v[2]; lo[3] = v[3];        \
                hi[0] = v[4]; hi[1] = v[5]; hi[2] = v[6]; hi[3] = v[7];        \
                *(short4v*)&As[(BUF) ^ 1][aw0[i]] = lo;                        \
                *(short4v*)&As[(BUF) ^ 1][aw1[i]] = hi;                        \
            }                                                                  \
            _Pragma("unroll")                                                  \
            for (int i = 0; i < 4; ++i) *(short4v*)&Bs[(BUF) ^ 1][bwidx[i]] = cvt4(rb[i]); \
        }                                                                      \
    }

__global__ __launch_bounds__(256, 3) void gemm2_kernel(
    const unsigned short* __restrict__ actb, const float* __restrict__ w2,
    const float* __restrict__ b2, const int* __restrict__ counts,
    const int* __restrict__ token_list, const float* __restrict__ weight_list,
    float* __restrict__ out) {
    int e = blockIdx.z;
    int cnt = counts[e];
    int m0 = blockIdx.y * 128;
    if (m0 >= cnt) return;
    int h0 = (blockIdx.x >> 1) * 64;
    int kbase = (blockIdx.x & 1) * 512;
    const float* w2e = w2 + (size_t)e * I_ * H_;
    const int* tl = token_list + e * T_;

    __shared__ __align__(16) short As[2][128 * 64];
    __shared__ __align__(16) short Bs[2][64 * 64];

    int tid = threadIdx.x;
    int lane = tid & 63;
    int wid = tid >> 6;
    int wm = wid >> 1, wn = wid & 1;
    int g = lane >> 4;
    int l15 = lane & 15;
    int sw = (l15 & 7) << 3;
    unsigned trb0 = (unsigned)(size_t)(&Bs[0][0]) + (unsigned)(lane * 8) + (unsigned)(wn * 4096);
    unsigned trb1 = (unsigned)(size_t)(&Bs[1][0]) + (unsigned)(lane * 8) + (unsigned)(wn * 4096);

    // A: 4 short8/thread from actb (dense per-expert rows)
    int q = tid & 7;
    const unsigned short* aptr[4]; int aw0[4], aw1[4];
#pragma unroll
    for (int i = 0; i < 4; ++i) {
        int row = i * 32 + (tid >> 3);
        int gr = m0 + row;
        aptr[i] = (gr < cnt) ? actb + (size_t)(e * T_ + gr) * I_ + kbase + q * 8 : nullptr;
        int swr = (row & 7) << 3;
        aw0[i] = row * 64 + (permpos(q * 8) ^ swr);
        aw1[i] = row * 64 + (permpos(q * 8 + 4) ^ swr);
    }
    // B: 4 float4/thread from w2
    int k4 = (tid & 15) << 2;
    const float* bptrB = w2e + (size_t)(kbase + (tid >> 4)) * H_ + h0 + k4;
    int bwidx[4];
#pragma unroll
    for (int i = 0; i < 4; ++i) {
        int krow = i * 16 + (tid >> 4);
        bwidx[i] = ((k4 >> 4) * 16 + (krow >> 2)) * 64 + (krow & 3) * 16 + (k4 & 15);
    }

    float4v acc[4][2];
#pragma unroll
    for (int i = 0; i < 4; ++i)
#pragma unroll
        for (int j = 0; j < 2; ++j) acc[i][j] = (float4v){0.f, 0.f, 0.f, 0.f};

    short8v ra2[4]; float4v rb[4];
    const short8v z8 = {0, 0, 0, 0, 0, 0, 0, 0};
    // prologue: tile 0 -> buf 0
#pragma unroll
    for (int i = 0; i < 4; ++i) ra2[i] = aptr[i] ? *(const short8v*)(aptr[i]) : z8;
#pragma unroll
    for (int i = 0; i < 4; ++i) rb[i] = *(const float4v*)(bptrB + (size_t)(i * 16) * H_);
#pragma unroll
    for (int i = 0; i < 4; ++i) {
        short8v v = ra2[i];
        short4v lo, hi;
        lo[0] = v[0]; lo[1] = v[1]; lo[2] = v[2]; lo[3] = v[3];
        hi[0] = v[4]; hi[1] = v[5]; hi[2] = v[6]; hi[3] = v[7];
        *(short4v*)&As[0][aw0[i]] = lo;
        *(short4v*)&As[0][aw1[i]] = hi;
    }
#pragma unroll
    for (int i = 0; i < 4; ++i) *(short4v*)&Bs[0][bwidx[i]] = cvt4(rb[i]);

#pragma unroll 1
    for (int kk = 0; kk < 512; kk += 128) {
        G2_STEP(0, kk + 64, false)
        G2_STEP(1, kk + 128, (kk + 128) >= 512)
    }

    const float* b2e = b2 + (size_t)e * H_;
    const float* wl = weight_list + e * T_;
    bool addbias = (kbase == 0);
#pragma unroll
    for (int mi = 0; mi < 4; ++mi) {
#pragma unroll
        for (int r = 0; r < 4; ++r) {
            int gm = m0 + wm * 64 + mi * 16 + g * 4 + r;
            if (gm < cnt) {
                int t = tl[gm];
                float wgt = wl[gm];
#pragma unroll
                for (int ni = 0; ni < 2; ++ni) {
                    int h = h0 + wn * 32 + ni * 16 + l15;
                    float v = acc[mi][ni][r];
                    if (addbias) v += b2e[h];
                    atomicAdd(&out[(size_t)t * H_ + h], v * wgt);
                }
            }
        }
    }
}

extern "C" void kernel_launch(void* const* d_in, const int* in_sizes, int n_in,
                              void* d_out, int out_size, void* d_ws, size_t ws_size,
                              hipStream_t stream) {
    const float* hs = (const float*)d_in[0];
    const float* gw = (const float*)d_in[1];
    const float* gb = (const float*)d_in[2];
    const float* w1 = (const float*)d_in[3];
    const float* b1 = (const float*)d_in[4];
    const float* w2 = (const float*)d_in[5];
    const float* b2 = (const float*)d_in[6];
    float* out = (float*)d_out;

    char* ws = (char*)d_ws;
    int*   counts      = (int*)ws;                       // 32 ints
    int*   token_list  = (int*)(ws + 4096);              // 32*1024 ints = 128 KB
    float* weight_list = (float*)(ws + 4096 + 131072);   // 32*1024 f32 = 128 KB
    unsigned short* actb = (unsigned short*)(ws + (1 << 20)); // 32*1024*1024 bf16 = 64 MB

    hipMemsetAsync(counts, 0, 32 * sizeof(int), stream);
    hipMemsetAsync(d_out, 0, (size_t)out_size * sizeof(float), stream);

    router_kernel<<<T_ / 4, 256, 0, stream>>>(hs, gw, gb, counts, token_list, weight_list);
    gemm1_kernel<<<dim3(TWO_I / 64, T_ / 128, E_), 256, 0, stream>>>(
        hs, w1, b1, counts, token_list, actb);
    gemm2_kernel<<<dim3((H_ / 64) * 2, T_ / 128, E_), 256, 0, stream>>>(
        actb, w2, b2, counts, token_list, weight_list, out);
}

// Round 5
// 203.874 us; speedup vs baseline: 4.7103x; 1.0536x over previous
//
#include <hip/hip_runtime.h>
#include <hip/hip_bf16.h>
#include <math.h>

#define E_ 32
#define K_ 4
#define H_ 1024
#define I_ 1024
#define T_ 1024
#define TWO_I 2048

typedef __attribute__((ext_vector_type(4))) float float4v;
typedef __attribute__((ext_vector_type(8))) short short8v;
typedef __attribute__((ext_vector_type(4))) short short4v;

__device__ __forceinline__ unsigned short f2bf(float f) {
    unsigned u = __float_as_uint(f);
    u = (u + 0x7FFFu + ((u >> 16) & 1u)) >> 16;   // RNE (epilogue scalar use only)
    return (unsigned short)u;
}
// packed RNE f32->bf16 via HW instruction: 2 els / instr
__device__ __forceinline__ short4v cvt4(float4v v) {
    union { unsigned u[2]; short4v s; } r;
    asm("v_cvt_pk_bf16_f32 %0, %1, %2" : "=v"(r.u[0]) : "v"(v[0]), "v"(v[1]));
    asm("v_cvt_pk_bf16_f32 %0, %1, %2" : "=v"(r.u[1]) : "v"(v[2]), "v"(v[3]));
    return r.s;
}
// permuted position (shorts) of a 4-aligned k-chunk in a 64-k row, matching
// tr-read k map: k = 32s + 16hi + 4g + j -> p = 32s + 8g + 4hi + j
__device__ __forceinline__ int permpos(int k4) {
    return ((k4 >> 5) << 5) + (((k4 >> 2) & 3) << 3) + (((k4 >> 4) & 1) << 2);
}

// ---------------- hs f32 -> bf16 (once; kills per-n-tile A re-conversion)
__global__ __launch_bounds__(256) void hs2bf_kernel(
    const float* __restrict__ hs, unsigned short* __restrict__ hsb) {
    int i = blockIdx.x * 256 + threadIdx.x;
    float4v v = *(const float4v*)(hs + (size_t)i * 4);
    *(short4v*)(hsb + (size_t)i * 4) = cvt4(v);
}

// ---------------- router: 4 tokens/block, one wave/token, wave-parallel top-4
__global__ __launch_bounds__(256) void router_kernel(
    const float* __restrict__ hs, const float* __restrict__ gw,
    const float* __restrict__ gb, int* __restrict__ counts,
    int* __restrict__ token_list, float* __restrict__ weight_list) {
    int wv = threadIdx.x >> 6, lane = threadIdx.x & 63;
    int t = blockIdx.x * 4 + wv;
    int e = lane & 31;
    int half = lane >> 5;
    const float* hrow = hs + (size_t)t * H_;
    const float* gcol = gw + e;
    float a0 = 0.f, a1 = 0.f;
    int hb = half * 512;
#pragma unroll 4
    for (int h = 0; h < 512; h += 2) {
        a0 = fmaf(hrow[hb + h],     gcol[(size_t)(hb + h) * E_], a0);
        a1 = fmaf(hrow[hb + h + 1], gcol[(size_t)(hb + h + 1) * E_], a1);
    }
    float part = a0 + a1;
    part += __shfl_xor(part, 32);
    float cur = part + gb[e];

    int idx4[K_]; float val4[K_];
#pragma unroll
    for (int k = 0; k < K_; ++k) {
        float m = cur;
#pragma unroll
        for (int d = 1; d < 64; d <<= 1) m = fmaxf(m, __shfl_xor(m, d));
        unsigned long long b = __ballot(cur == m);
        int l = __ffsll(b) - 1;          // lowest lane -> lowest expert idx (tie-break)
        idx4[k] = l & 31; val4[k] = m;
        if (e == (l & 31)) cur = -INFINITY;
    }
    float mx = val4[0], s = 0.f, wv4[K_];
#pragma unroll
    for (int k = 0; k < K_; ++k) { wv4[k] = expf(val4[k] - mx); s += wv4[k]; }
    float inv = 1.f / s;
    if (lane < K_) {
        int ex = idx4[lane];
        int slot = atomicAdd(&counts[ex], 1);
        token_list[ex * T_ + slot] = t;
        weight_list[ex * T_ + slot] = wv4[lane] * inv;
    }
}

// ---------------- shared MFMA compute phase (BM=128 x BN=64, BK=64, 4 waves)
#define G_COMPUTE(BUF)                                                         \
    _Pragma("unroll")                                                          \
    for (int s = 0; s < 2; ++s) {                                              \
        short8v afr[4];                                                        \
        _Pragma("unroll")                                                      \
        for (int mi = 0; mi < 4; ++mi) {                                       \
            int row = wm * 64 + mi * 16 + l15;                                 \
            afr[mi] = *(const short8v*)&As[BUF][row * 64 + ((s * 32 + g * 8) ^ sw)]; \
        }                                                                      \
        short4v bl[2], bh[2];                                                  \
        _Pragma("unroll")                                                      \
        for (int ni = 0; ni < 2; ++ni) {                                       \
            unsigned ad = ((BUF) ? trb1 : trb0) + (unsigned)(ni * 2048 + s * 1024); \
            asm volatile("ds_read_b64_tr_b16 %0, %1" : "=v"(bl[ni]) : "v"(ad));     \
            asm volatile("ds_read_b64_tr_b16 %0, %1" : "=v"(bh[ni]) : "v"(ad + 512u)); \
        }                                                                      \
        asm volatile("s_waitcnt lgkmcnt(0)" ::: "memory");                     \
        __builtin_amdgcn_sched_barrier(0);                                     \
        _Pragma("unroll")                                                      \
        for (int ni = 0; ni < 2; ++ni) {                                       \
            short8v b;                                                         \
            b[0] = bl[ni][0]; b[1] = bl[ni][1]; b[2] = bl[ni][2]; b[3] = bl[ni][3]; \
            b[4] = bh[ni][0]; b[5] = bh[ni][1]; b[6] = bh[ni][2]; b[7] = bh[ni][3]; \
            _Pragma("unroll")                                                  \
            for (int mi = 0; mi < 4; ++mi)                                     \
                acc[mi][ni] = __builtin_amdgcn_mfma_f32_16x16x32_bf16(afr[mi], b, acc[mi][ni], 0, 0, 0); \
        }                                                                      \
    }

// ---------------- shared K-step: bf16 A (4x short8), f32 B (4x float4 -> cvt_pk)
#define G_STEP(BUF, KN, BSTRIDE, ISLAST)                                       \
    {                                                                          \
        __syncthreads();                                                       \
        if (!(ISLAST)) {                                                       \
            _Pragma("unroll")                                                  \
            for (int i = 0; i < 4; ++i)                                        \
                ra[i] = aptr[i] ? *(const short8v*)(aptr[i] + (KN)) : z8;      \
            _Pragma("unroll")                                                  \
            for (int i = 0; i < 4; ++i)                                        \
                rb[i] = *(const float4v*)(bptrB + (size_t)(KN) * (BSTRIDE) + (size_t)(i * 16) * (BSTRIDE)); \
        }                                                                      \
        __builtin_amdgcn_sched_barrier(0);                                     \
        G_COMPUTE(BUF)                                                         \
        if (!(ISLAST)) {                                                       \
            _Pragma("unroll")                                                  \
            for (int i = 0; i < 4; ++i) {                                      \
                short8v v = ra[i];                                             \
                short4v lo, hi;                                                \
                lo[0] = v[0]; lo[1] = v[1]; lo[2] = v[2]; lo[3] = v[3];        \
                hi[0] = v[4]; hi[1] = v[5]; hi[2] = v[6]; hi[3] = v[7];        \
                *(short4v*)&As[(BUF) ^ 1][aw0[i]] = lo;                        \
                *(short4v*)&As[(BUF) ^ 1][aw1[i]] = hi;                        \
            }                                                                  \
            _Pragma("unroll")                                                  \
            for (int i = 0; i < 4; ++i) *(short4v*)&Bs[(BUF) ^ 1][bwidx[i]] = cvt4(rb[i]); \
        }                                                                      \
    }

// ---------------- GEMM1 (bf16 MFMA, dbuf) + swiglu
__global__ __launch_bounds__(256, 3) void gemm1_kernel(
    const unsigned short* __restrict__ hsb, const float* __restrict__ w1,
    const float* __restrict__ b1, const int* __restrict__ counts,
    const int* __restrict__ token_list, unsigned short* __restrict__ actb) {
    int e = blockIdx.z;
    int cnt = counts[e];
    int m0 = blockIdx.y * 128;
    if (m0 >= cnt) return;
    int cb = blockIdx.x * 64;              // w1 col base
    const float* w1e = w1 + (size_t)e * H_ * TWO_I;
    const int* tl = token_list + e * T_;

    __shared__ __align__(16) short As[2][128 * 64];  // 32 KB
    __shared__ __align__(16) short Bs[2][64 * 64];   // 16 KB

    int tid = threadIdx.x;
    int lane = tid & 63;
    int wid = tid >> 6;
    int wm = wid >> 1, wn = wid & 1;
    int g = lane >> 4;
    int l15 = lane & 15;
    int sw = (l15 & 7) << 3;
    unsigned trb0 = (unsigned)(size_t)(&Bs[0][0]) + (unsigned)(lane * 8) + (unsigned)(wn * 4096);
    unsigned trb1 = (unsigned)(size_t)(&Bs[1][0]) + (unsigned)(lane * 8) + (unsigned)(wn * 4096);

    // A: 4 short8/thread (gathered bf16 token rows)
    int q = tid & 7;
    const unsigned short* aptr[4]; int aw0[4], aw1[4];
#pragma unroll
    for (int i = 0; i < 4; ++i) {
        int row = i * 32 + (tid >> 3);
        int gr = m0 + row;
        aptr[i] = (gr < cnt) ? hsb + (size_t)tl[gr] * H_ + q * 8 : nullptr;
        int swr = (row & 7) << 3;
        aw0[i] = row * 64 + (permpos(q * 8) ^ swr);
        aw1[i] = row * 64 + (permpos(q * 8 + 4) ^ swr);
    }
    // B: 4 float4/thread; k-rows (tid>>4)+16i, cols cb + (tid&15)*4
    int c4 = (tid & 15) << 2;
    const float* bptrB = w1e + (size_t)(tid >> 4) * TWO_I + cb + c4;
    int bwidx[4];
#pragma unroll
    for (int i = 0; i < 4; ++i) {
        int krow = i * 16 + (tid >> 4);
        bwidx[i] = ((c4 >> 4) * 16 + (krow >> 2)) * 64 + (krow & 3) * 16 + (c4 & 15);
    }

    float4v acc[4][2];
#pragma unroll
    for (int i = 0; i < 4; ++i)
#pragma unroll
        for (int j = 0; j < 2; ++j) acc[i][j] = (float4v){0.f, 0.f, 0.f, 0.f};

    short8v ra[4]; float4v rb[4];
    const short8v z8 = {0, 0, 0, 0, 0, 0, 0, 0};
    // prologue: tile 0 -> buf 0
#pragma unroll
    for (int i = 0; i < 4; ++i) ra[i] = aptr[i] ? *(const short8v*)(aptr[i]) : z8;
#pragma unroll
    for (int i = 0; i < 4; ++i) rb[i] = *(const float4v*)(bptrB + (size_t)(i * 16) * TWO_I);
#pragma unroll
    for (int i = 0; i < 4; ++i) {
        short8v v = ra[i];
        short4v lo, hi;
        lo[0] = v[0]; lo[1] = v[1]; lo[2] = v[2]; lo[3] = v[3];
        hi[0] = v[4]; hi[1] = v[5]; hi[2] = v[6]; hi[3] = v[7];
        *(short4v*)&As[0][aw0[i]] = lo;
        *(short4v*)&As[0][aw1[i]] = hi;
    }
#pragma unroll
    for (int i = 0; i < 4; ++i) *(short4v*)&Bs[0][bwidx[i]] = cvt4(rb[i]);

#pragma unroll 1
    for (int kk = 0; kk < H_; kk += 128) {
        G_STEP(0, kk + 64, TWO_I, false)
        G_STEP(1, kk + 128, TWO_I, (kk + 128) >= H_)
    }

    // epilogue: deinterleave gate/up (adjacent lanes), swiglu, store bf16 act
    const float* b1e = b1 + (size_t)e * TWO_I;
#pragma unroll
    for (int mi = 0; mi < 4; ++mi) {
#pragma unroll
        for (int r = 0; r < 4; ++r) {
            int gm = m0 + wm * 64 + mi * 16 + g * 4 + r;
#pragma unroll
            for (int ni = 0; ni < 2; ++ni) {
                float v = acc[mi][ni][r];
                float o = __shfl_xor(v, 1);
                if (!(lane & 1) && gm < cnt) {
                    int wc = cb + wn * 32 + ni * 16 + l15;   // even w1 col (gate)
                    float gate = v + b1e[wc];
                    float up   = o + b1e[wc + 1];
                    float sg = 1.f / (1.f + __expf(-1.702f * gate));
                    float av = (up + 1.f) * gate * sg;
                    actb[(size_t)(e * T_ + gm) * I_ + (wc >> 1)] = f2bf(av);
                }
            }
        }
    }
}

// ---------------- GEMM2 (bf16 MFMA, dbuf, K-split x2) + weighted scatter
__global__ __launch_bounds__(256, 3) void gemm2_kernel(
    const unsigned short* __restrict__ actb, const float* __restrict__ w2,
    const float* __restrict__ b2, const int* __restrict__ counts,
    const int* __restrict__ token_list, const float* __restrict__ weight_list,
    float* __restrict__ out) {
    int e = blockIdx.z;
    int cnt = counts[e];
    int m0 = blockIdx.y * 128;
    if (m0 >= cnt) return;
    int h0 = (blockIdx.x >> 1) * 64;
    int kbase = (blockIdx.x & 1) * 512;
    const float* w2e = w2 + (size_t)e * I_ * H_;
    const int* tl = token_list + e * T_;

    __shared__ __align__(16) short As[2][128 * 64];
    __shared__ __align__(16) short Bs[2][64 * 64];

    int tid = threadIdx.x;
    int lane = tid & 63;
    int wid = tid >> 6;
    int wm = wid >> 1, wn = wid & 1;
    int g = lane >> 4;
    int l15 = lane & 15;
    int sw = (l15 & 7) << 3;
    unsigned trb0 = (unsigned)(size_t)(&Bs[0][0]) + (unsigned)(lane * 8) + (unsigned)(wn * 4096);
    unsigned trb1 = (unsigned)(size_t)(&Bs[1][0]) + (unsigned)(lane * 8) + (unsigned)(wn * 4096);

    // A: 4 short8/thread from actb (dense per-expert rows)
    int q = tid & 7;
    const unsigned short* aptr[4]; int aw0[4], aw1[4];
#pragma unroll
    for (int i = 0; i < 4; ++i) {
        int row = i * 32 + (tid >> 3);
        int gr = m0 + row;
        aptr[i] = (gr < cnt) ? actb + (size_t)(e * T_ + gr) * I_ + kbase + q * 8 : nullptr;
        int swr = (row & 7) << 3;
        aw0[i] = row * 64 + (permpos(q * 8) ^ swr);
        aw1[i] = row * 64 + (permpos(q * 8 + 4) ^ swr);
    }
    // B: 4 float4/thread from w2
    int c4 = (tid & 15) << 2;
    const float* bptrB = w2e + (size_t)(kbase + (tid >> 4)) * H_ + h0 + c4;
    int bwidx[4];
#pragma unroll
    for (int i = 0; i < 4; ++i) {
        int krow = i * 16 + (tid >> 4);
        bwidx[i] = ((c4 >> 4) * 16 + (krow >> 2)) * 64 + (krow & 3) * 16 + (c4 & 15);
    }

    float4v acc[4][2];
#pragma unroll
    for (int i = 0; i < 4; ++i)
#pragma unroll
        for (int j = 0; j < 2; ++j) acc[i][j] = (float4v){0.f, 0.f, 0.f, 0.f};

    short8v ra[4]; float4v rb[4];
    const short8v z8 = {0, 0, 0, 0, 0, 0, 0, 0};
    // prologue: tile 0 -> buf 0
#pragma unroll
    for (int i = 0; i < 4; ++i) ra[i] = aptr[i] ? *(const short8v*)(aptr[i]) : z8;
#pragma unroll
    for (int i = 0; i < 4; ++i) rb[i] = *(const float4v*)(bptrB + (size_t)(i * 16) * H_);
#pragma unroll
    for (int i = 0; i < 4; ++i) {
        short8v v = ra[i];
        short4v lo, hi;
        lo[0] = v[0]; lo[1] = v[1]; lo[2] = v[2]; lo[3] = v[3];
        hi[0] = v[4]; hi[1] = v[5]; hi[2] = v[6]; hi[3] = v[7];
        *(short4v*)&As[0][aw0[i]] = lo;
        *(short4v*)&As[0][aw1[i]] = hi;
    }
#pragma unroll
    for (int i = 0; i < 4; ++i) *(short4v*)&Bs[0][bwidx[i]] = cvt4(rb[i]);

#pragma unroll 1
    for (int kk = 0; kk < 512; kk += 128) {
        G_STEP(0, kk + 64, H_, false)
        G_STEP(1, kk + 128, H_, (kk + 128) >= 512)
    }

    const float* b2e = b2 + (size_t)e * H_;
    const float* wl = weight_list + e * T_;
    bool addbias = (kbase == 0);
#pragma unroll
    for (int mi = 0; mi < 4; ++mi) {
#pragma unroll
        for (int r = 0; r < 4; ++r) {
            int gm = m0 + wm * 64 + mi * 16 + g * 4 + r;
            if (gm < cnt) {
                int t = tl[gm];
                float wgt = wl[gm];
#pragma unroll
                for (int ni = 0; ni < 2; ++ni) {
                    int h = h0 + wn * 32 + ni * 16 + l15;
                    float v = acc[mi][ni][r];
                    if (addbias) v += b2e[h];
                    atomicAdd(&out[(size_t)t * H_ + h], v * wgt);
                }
            }
        }
    }
}

extern "C" void kernel_launch(void* const* d_in, const int* in_sizes, int n_in,
                              void* d_out, int out_size, void* d_ws, size_t ws_size,
                              hipStream_t stream) {
    const float* hs = (const float*)d_in[0];
    const float* gw = (const float*)d_in[1];
    const float* gb = (const float*)d_in[2];
    const float* w1 = (const float*)d_in[3];
    const float* b1 = (const float*)d_in[4];
    const float* w2 = (const float*)d_in[5];
    const float* b2 = (const float*)d_in[6];
    float* out = (float*)d_out;

    char* ws = (char*)d_ws;
    int*   counts      = (int*)ws;                         // 32 ints
    int*   token_list  = (int*)(ws + 4096);                // 32*1024 ints
    float* weight_list = (float*)(ws + 4096 + 131072);     // 32*1024 f32
    unsigned short* hsb  = (unsigned short*)(ws + (1 << 20));        // 2 MB
    unsigned short* actb = (unsigned short*)(ws + (1 << 20) + (2 << 20)); // 64 MB

    hipMemsetAsync(counts, 0, 32 * sizeof(int), stream);
    hipMemsetAsync(d_out, 0, (size_t)out_size * sizeof(float), stream);

    hs2bf_kernel<<<(T_ * H_ / 4) / 256, 256, 0, stream>>>(hs, hsb);
    router_kernel<<<T_ / 4, 256, 0, stream>>>(hs, gw, gb, counts, token_list, weight_list);
    gemm1_kernel<<<dim3(TWO_I / 64, T_ / 128, E_), 256, 0, stream>>>(
        hsb, w1, b1, counts, token_list, actb);
    gemm2_kernel<<<dim3((H_ / 64) * 2, T_ / 128, E_), 256, 0, stream>>>(
        actb, w2, b2, counts, token_list, weight_list, out);
}

// Round 7
// 201.606 us; speedup vs baseline: 4.7633x; 1.0113x over previous
//
#include <hip/hip_runtime.h>
#include <hip/hip_bf16.h>
#include <math.h>

#define E_ 32
#define K_ 4
#define H_ 1024
#define I_ 1024
#define T_ 1024
#define TWO_I 2048

typedef __attribute__((ext_vector_type(4))) float float4v;
typedef __attribute__((ext_vector_type(8))) short short8v;
typedef __attribute__((ext_vector_type(4))) short short4v;

__device__ __forceinline__ unsigned short f2bf(float f) {
    unsigned u = __float_as_uint(f);
    u = (u + 0x7FFFu + ((u >> 16) & 1u)) >> 16;   // RNE (epilogue scalar use only)
    return (unsigned short)u;
}
// packed RNE f32->bf16 via HW instruction: 2 els / instr
__device__ __forceinline__ short4v cvt4(float4v v) {
    union { unsigned u[2]; short4v s; } r;
    asm("v_cvt_pk_bf16_f32 %0, %1, %2" : "=v"(r.u[0]) : "v"(v[0]), "v"(v[1]));
    asm("v_cvt_pk_bf16_f32 %0, %1, %2" : "=v"(r.u[1]) : "v"(v[2]), "v"(v[3]));
    return r.s;
}
// permuted position (shorts) of a 4-aligned k-chunk in a 64-k row, matching
// tr-read k map: k = 32s + 16hi + 4g + j -> p = 32s + 8g + 4hi + j
__device__ __forceinline__ int permpos(int k4) {
    return ((k4 >> 5) << 5) + (((k4 >> 2) & 3) << 3) + (((k4 >> 4) & 1) << 2);
}

// ---------------- zero out + counts (replaces slow rocclr fills)
__global__ __launch_bounds__(256) void zero_kernel(float* __restrict__ out,
                                                   int* __restrict__ counts) {
    int i = blockIdx.x * 256 + threadIdx.x;
    *(float4v*)(out + (size_t)i * 4) = (float4v){0.f, 0.f, 0.f, 0.f};
    if (blockIdx.x == 0 && threadIdx.x < E_) counts[threadIdx.x] = 0;
}

// ---------------- hs f32 -> bf16 (once; kills per-n-tile A re-conversion)
__global__ __launch_bounds__(256) void hs2bf_kernel(
    const float* __restrict__ hs, unsigned short* __restrict__ hsb) {
    int i = blockIdx.x * 256 + threadIdx.x;
    float4v v = *(const float4v*)(hs + (size_t)i * 4);
    *(short4v*)(hsb + (size_t)i * 4) = cvt4(v);
}

// ---------------- router: 4 tokens/block, one wave/token, wave-parallel top-4
__global__ __launch_bounds__(256) void router_kernel(
    const float* __restrict__ hs, const float* __restrict__ gw,
    const float* __restrict__ gb, int* __restrict__ counts,
    int* __restrict__ token_list, float* __restrict__ weight_list) {
    int wv = threadIdx.x >> 6, lane = threadIdx.x & 63;
    int t = blockIdx.x * 4 + wv;
    int e = lane & 31;
    int half = lane >> 5;
    const float* hrow = hs + (size_t)t * H_;
    const float* gcol = gw + e;
    float a0 = 0.f, a1 = 0.f;
    int hb = half * 512;
#pragma unroll 4
    for (int h = 0; h < 512; h += 2) {
        a0 = fmaf(hrow[hb + h],     gcol[(size_t)(hb + h) * E_], a0);
        a1 = fmaf(hrow[hb + h + 1], gcol[(size_t)(hb + h + 1) * E_], a1);
    }
    float part = a0 + a1;
    part += __shfl_xor(part, 32);
    float cur = part + gb[e];

    int idx4[K_]; float val4[K_];
#pragma unroll
    for (int k = 0; k < K_; ++k) {
        float m = cur;
#pragma unroll
        for (int d = 1; d < 64; d <<= 1) m = fmaxf(m, __shfl_xor(m, d));
        unsigned long long b = __ballot(cur == m);
        int l = __ffsll(b) - 1;          // lowest lane -> lowest expert idx (tie-break)
        idx4[k] = l & 31; val4[k] = m;
        if (e == (l & 31)) cur = -INFINITY;
    }
    float mx = val4[0], s = 0.f, wv4[K_];
#pragma unroll
    for (int k = 0; k < K_; ++k) { wv4[k] = expf(val4[k] - mx); s += wv4[k]; }
    float inv = 1.f / s;
    if (lane < K_) {
        int ex = idx4[lane];
        int slot = atomicAdd(&counts[ex], 1);
        token_list[ex * T_ + slot] = t;
        weight_list[ex * T_ + slot] = wv4[lane] * inv;
    }
}

// ---------------- shared MFMA compute phase (BM=128 x BN=64, BK=64, 4 waves)
#define G_COMPUTE(BUF)                                                         \
    _Pragma("unroll")                                                          \
    for (int s = 0; s < 2; ++s) {                                              \
        short8v afr[4];                                                        \
        _Pragma("unroll")                                                      \
        for (int mi = 0; mi < 4; ++mi) {                                       \
            int row = wm * 64 + mi * 16 + l15;                                 \
            afr[mi] = *(const short8v*)&As[BUF][row * 64 + ((s * 32 + g * 8) ^ sw)]; \
        }                                                                      \
        short4v bl[2], bh[2];                                                  \
        _Pragma("unroll")                                                      \
        for (int ni = 0; ni < 2; ++ni) {                                       \
            unsigned ad = ((BUF) ? trb1 : trb0) + (unsigned)(ni * 2048 + s * 1024); \
            asm volatile("ds_read_b64_tr_b16 %0, %1" : "=v"(bl[ni]) : "v"(ad));     \
            asm volatile("ds_read_b64_tr_b16 %0, %1" : "=v"(bh[ni]) : "v"(ad + 512u)); \
        }                                                                      \
        asm volatile("s_waitcnt lgkmcnt(0)" ::: "memory");                     \
        __builtin_amdgcn_sched_barrier(0);                                     \
        _Pragma("unroll")                                                      \
        for (int ni = 0; ni < 2; ++ni) {                                       \
            short8v b;                                                         \
            b[0] = bl[ni][0]; b[1] = bl[ni][1]; b[2] = bl[ni][2]; b[3] = bl[ni][3]; \
            b[4] = bh[ni][0]; b[5] = bh[ni][1]; b[6] = bh[ni][2]; b[7] = bh[ni][3]; \
            _Pragma("unroll")                                                  \
            for (int mi = 0; mi < 4; ++mi)                                     \
                acc[mi][ni] = __builtin_amdgcn_mfma_f32_16x16x32_bf16(afr[mi], b, acc[mi][ni], 0, 0, 0); \
        }                                                                      \
    }

// ---------------- shared K-step: bf16 A (4x short8), f32 B (4x float4 -> cvt_pk)
#define G_STEP(BUF, KN, BSTRIDE, ISLAST)                                       \
    {                                                                          \
        __syncthreads();                                                       \
        if (!(ISLAST)) {                                                       \
            _Pragma("unroll")                                                  \
            for (int i = 0; i < 4; ++i)                                        \
                ra[i] = aptr[i] ? *(const short8v*)(aptr[i] + (KN)) : z8;      \
            _Pragma("unroll")                                                  \
            for (int i = 0; i < 4; ++i)                                        \
                rb[i] = *(const float4v*)(bptrB + (size_t)(KN) * (BSTRIDE) + (size_t)(i * 16) * (BSTRIDE)); \
        }                                                                      \
        __builtin_amdgcn_sched_barrier(0);                                     \
        G_COMPUTE(BUF)                                                         \
        if (!(ISLAST)) {                                                       \
            _Pragma("unroll")                                                  \
            for (int i = 0; i < 4; ++i) {                                      \
                short8v v = ra[i];                                             \
                short4v lo, hi;                                                \
                lo[0] = v[0]; lo[1] = v[1]; lo[2] = v[2]; lo[3] = v[3];        \
                hi[0] = v[4]; hi[1] = v[5]; hi[2] = v[6]; hi[3] = v[7];        \
                *(short4v*)&As[(BUF) ^ 1][aw0[i]] = lo;                        \
                *(short4v*)&As[(BUF) ^ 1][aw1[i]] = hi;                        \
            }                                                                  \
            _Pragma("unroll")                                                  \
            for (int i = 0; i < 4; ++i) *(short4v*)&Bs[(BUF) ^ 1][bwidx[i]] = cvt4(rb[i]); \
        }                                                                      \
    }

// ---------------- GEMM1 (bf16 MFMA, dbuf) + swiglu
__global__ __launch_bounds__(256, 3) void gemm1_kernel(
    const unsigned short* __restrict__ hsb, const float* __restrict__ w1,
    const float* __restrict__ b1, const int* __restrict__ counts,
    const int* __restrict__ token_list, unsigned short* __restrict__ actb) {
    int e = blockIdx.z;
    int cnt = counts[e];
    int m0 = blockIdx.y * 128;
    if (m0 >= cnt) return;
    int cb = blockIdx.x * 64;              // w1 col base
    const float* w1e = w1 + (size_t)e * H_ * TWO_I;
    const int* tl = token_list + e * T_;

    __shared__ __align__(16) short As[2][128 * 64];  // 32 KB
    __shared__ __align__(16) short Bs[2][64 * 64];   // 16 KB

    int tid = threadIdx.x;
    int lane = tid & 63;
    int wid = tid >> 6;
    int wm = wid >> 1, wn = wid & 1;
    int g = lane >> 4;
    int l15 = lane & 15;
    int sw = (l15 & 7) << 3;
    unsigned trb0 = (unsigned)(size_t)(&Bs[0][0]) + (unsigned)(lane * 8) + (unsigned)(wn * 4096);
    unsigned trb1 = (unsigned)(size_t)(&Bs[1][0]) + (unsigned)(lane * 8) + (unsigned)(wn * 4096);

    // A: 4 short8/thread (gathered bf16 token rows)
    int q = tid & 7;
    const unsigned short* aptr[4]; int aw0[4], aw1[4];
#pragma unroll
    for (int i = 0; i < 4; ++i) {
        int row = i * 32 + (tid >> 3);
        int gr = m0 + row;
        aptr[i] = (gr < cnt) ? hsb + (size_t)tl[gr] * H_ + q * 8 : nullptr;
        int swr = (row & 7) << 3;
        aw0[i] = row * 64 + (permpos(q * 8) ^ swr);
        aw1[i] = row * 64 + (permpos(q * 8 + 4) ^ swr);
    }
    // B: 4 float4/thread; k-rows (tid>>4)+16i, cols cb + (tid&15)*4
    int c4 = (tid & 15) << 2;
    const float* bptrB = w1e + (size_t)(tid >> 4) * TWO_I + cb + c4;
    int bwidx[4];
#pragma unroll
    for (int i = 0; i < 4; ++i) {
        int krow = i * 16 + (tid >> 4);
        bwidx[i] = ((c4 >> 4) * 16 + (krow >> 2)) * 64 + (krow & 3) * 16 + (c4 & 15);
    }

    float4v acc[4][2];
#pragma unroll
    for (int i = 0; i < 4; ++i)
#pragma unroll
        for (int j = 0; j < 2; ++j) acc[i][j] = (float4v){0.f, 0.f, 0.f, 0.f};

    short8v ra[4]; float4v rb[4];
    const short8v z8 = {0, 0, 0, 0, 0, 0, 0, 0};
    // prologue: tile 0 -> buf 0
#pragma unroll
    for (int i = 0; i < 4; ++i) ra[i] = aptr[i] ? *(const short8v*)(aptr[i]) : z8;
#pragma unroll
    for (int i = 0; i < 4; ++i) rb[i] = *(const float4v*)(bptrB + (size_t)(i * 16) * TWO_I);
#pragma unroll
    for (int i = 0; i < 4; ++i) {
        short8v v = ra[i];
        short4v lo, hi;
        lo[0] = v[0]; lo[1] = v[1]; lo[2] = v[2]; lo[3] = v[3];
        hi[0] = v[4]; hi[1] = v[5]; hi[2] = v[6]; hi[3] = v[7];
        *(short4v*)&As[0][aw0[i]] = lo;
        *(short4v*)&As[0][aw1[i]] = hi;
    }
#pragma unroll
    for (int i = 0; i < 4; ++i) *(short4v*)&Bs[0][bwidx[i]] = cvt4(rb[i]);

#pragma unroll 1
    for (int kk = 0; kk < H_; kk += 128) {
        G_STEP(0, kk + 64, TWO_I, false)
        G_STEP(1, kk + 128, TWO_I, (kk + 128) >= H_)
    }

    // epilogue: deinterleave gate/up (adjacent lanes), swiglu, store bf16 act
    const float* b1e = b1 + (size_t)e * TWO_I;
#pragma unroll
    for (int mi = 0; mi < 4; ++mi) {
#pragma unroll
        for (int r = 0; r < 4; ++r) {
            int gm = m0 + wm * 64 + mi * 16 + g * 4 + r;
#pragma unroll
            for (int ni = 0; ni < 2; ++ni) {
                float v = acc[mi][ni][r];
                float o = __shfl_xor(v, 1);
                if (!(lane & 1) && gm < cnt) {
                    int wc = cb + wn * 32 + ni * 16 + l15;   // even w1 col (gate)
                    float gate = v + b1e[wc];
                    float up   = o + b1e[wc + 1];
                    float sg = 1.f / (1.f + __expf(-1.702f * gate));
                    float av = (up + 1.f) * gate * sg;
                    actb[(size_t)(e * T_ + gm) * I_ + (wc >> 1)] = f2bf(av);
                }
            }
        }
    }
}

// ---------------- GEMM2 (bf16 MFMA, dbuf, K-split x2) + weighted scatter
__global__ __launch_bounds__(256, 3) void gemm2_kernel(
    const unsigned short* __restrict__ actb, const float* __restrict__ w2,
    const float* __restrict__ b2, const int* __restrict__ counts,
    const int* __restrict__ token_list, const float* __restrict__ weight_list,
    float* __restrict__ out) {
    int e = blockIdx.z;
    int cnt = counts[e];
    int m0 = blockIdx.y * 128;
    if (m0 >= cnt) return;
    int h0 = (blockIdx.x >> 1) * 64;
    int kbase = (blockIdx.x & 1) * 512;
    const float* w2e = w2 + (size_t)e * I_ * H_;
    const int* tl = token_list + e * T_;

    __shared__ __align__(16) short As[2][128 * 64];
    __shared__ __align__(16) short Bs[2][64 * 64];

    int tid = threadIdx.x;
    int lane = tid & 63;
    int wid = tid >> 6;
    int wm = wid >> 1, wn = wid & 1;
    int g = lane >> 4;
    int l15 = lane & 15;
    int sw = (l15 & 7) << 3;
    unsigned trb0 = (unsigned)(size_t)(&Bs[0][0]) + (unsigned)(lane * 8) + (unsigned)(wn * 4096);
    unsigned trb1 = (unsigned)(size_t)(&Bs[1][0]) + (unsigned)(lane * 8) + (unsigned)(wn * 4096);

    // A: 4 short8/thread from actb (dense per-expert rows)
    int q = tid & 7;
    const unsigned short* aptr[4]; int aw0[4], aw1[4];
#pragma unroll
    for (int i = 0; i < 4; ++i) {
        int row = i * 32 + (tid >> 3);
        int gr = m0 + row;
        aptr[i] = (gr < cnt) ? actb + (size_t)(e * T_ + gr) * I_ + kbase + q * 8 : nullptr;
        int swr = (row & 7) << 3;
        aw0[i] = row * 64 + (permpos(q * 8) ^ swr);
        aw1[i] = row * 64 + (permpos(q * 8 + 4) ^ swr);
    }
    // B: 4 float4/thread from w2
    int c4 = (tid & 15) << 2;
    const float* bptrB = w2e + (size_t)(kbase + (tid >> 4)) * H_ + h0 + c4;
    int bwidx[4];
#pragma unroll
    for (int i = 0; i < 4; ++i) {
        int krow = i * 16 + (tid >> 4);
        bwidx[i] = ((c4 >> 4) * 16 + (krow >> 2)) * 64 + (krow & 3) * 16 + (c4 & 15);
    }

    float4v acc[4][2];
#pragma unroll
    for (int i = 0; i < 4; ++i)
#pragma unroll
        for (int j = 0; j < 2; ++j) acc[i][j] = (float4v){0.f, 0.f, 0.f, 0.f};

    short8v ra[4]; float4v rb[4];
    const short8v z8 = {0, 0, 0, 0, 0, 0, 0, 0};
    // prologue: tile 0 -> buf 0
#pragma unroll
    for (int i = 0; i < 4; ++i) ra[i] = aptr[i] ? *(const short8v*)(aptr[i]) : z8;
#pragma unroll
    for (int i = 0; i < 4; ++i) rb[i] = *(const float4v*)(bptrB + (size_t)(i * 16) * H_);
#pragma unroll
    for (int i = 0; i < 4; ++i) {
        short8v v = ra[i];
        short4v lo, hi;
        lo[0] = v[0]; lo[1] = v[1]; lo[2] = v[2]; lo[3] = v[3];
        hi[0] = v[4]; hi[1] = v[5]; hi[2] = v[6]; hi[3] = v[7];
        *(short4v*)&As[0][aw0[i]] = lo;
        *(short4v*)&As[0][aw1[i]] = hi;
    }
#pragma unroll
    for (int i = 0; i < 4; ++i) *(short4v*)&Bs[0][bwidx[i]] = cvt4(rb[i]);

#pragma unroll 1
    for (int kk = 0; kk < 512; kk += 128) {
        G_STEP(0, kk + 64, H_, false)
        G_STEP(1, kk + 128, H_, (kk + 128) >= 512)
    }

    const float* b2e = b2 + (size_t)e * H_;
    const float* wl = weight_list + e * T_;
    bool addbias = (kbase == 0);
#pragma unroll
    for (int mi = 0; mi < 4; ++mi) {
#pragma unroll
        for (int r = 0; r < 4; ++r) {
            int gm = m0 + wm * 64 + mi * 16 + g * 4 + r;
            if (gm < cnt) {
                int t = tl[gm];
                float wgt = wl[gm];
#pragma unroll
                for (int ni = 0; ni < 2; ++ni) {
                    int h = h0 + wn * 32 + ni * 16 + l15;
                    float v = acc[mi][ni][r];
                    if (addbias) v += b2e[h];
                    atomicAdd(&out[(size_t)t * H_ + h], v * wgt);
                }
            }
        }
    }
}

extern "C" void kernel_launch(void* const* d_in, const int* in_sizes, int n_in,
                              void* d_out, int out_size, void* d_ws, size_t ws_size,
                              hipStream_t stream) {
    const float* hs = (const float*)d_in[0];
    const float* gw = (const float*)d_in[1];
    const float* gb = (const float*)d_in[2];
    const float* w1 = (const float*)d_in[3];
    const float* b1 = (const float*)d_in[4];
    const float* w2 = (const float*)d_in[5];
    const float* b2 = (const float*)d_in[6];
    float* out = (float*)d_out;

    char* ws = (char*)d_ws;
    int*   counts      = (int*)ws;                         // 32 ints
    int*   token_list  = (int*)(ws + 4096);                // 32*1024 ints
    float* weight_list = (float*)(ws + 4096 + 131072);     // 32*1024 f32
    unsigned short* hsb  = (unsigned short*)(ws + (1 << 20));        // 2 MB
    unsigned short* actb = (unsigned short*)(ws + (1 << 20) + (2 << 20)); // 64 MB

    zero_kernel<<<(T_ * H_ / 4) / 256, 256, 0, stream>>>(out, counts);
    hs2bf_kernel<<<(T_ * H_ / 4) / 256, 256, 0, stream>>>(hs, hsb);
    router_kernel<<<T_ / 4, 256, 0, stream>>>(hs, gw, gb, counts, token_list, weight_list);
    gemm1_kernel<<<dim3(TWO_I / 64, T_ / 128, E_), 256, 0, stream>>>(
        hsb, w1, b1, counts, token_list, actb);
    gemm2_kernel<<<dim3((H_ / 64) * 2, T_ / 128, E_), 256, 0, stream>>>(
        actb, w2, b2, counts, token_list, weight_list, out);
}